// Round 16
// baseline (435.293 us; speedup 1.0000x reference)
//
#include <hip/hip_runtime.h>
#include <hip/hip_bf16.h>

typedef __bf16 bf16;
typedef __attribute__((ext_vector_type(8))) __bf16 bf16x8;
typedef __attribute__((ext_vector_type(4))) __bf16 bf16x4;
typedef __attribute__((ext_vector_type(4))) float f32x4;
typedef __attribute__((ext_vector_type(16))) float f32x16;

#define NB 2
#define NT 2048
#define ND 1024
#define NH 16
#define HD_ 64
#define NE 8
#define NCAP 640
#define NTOK 4096
#define NDFF 4096

static __device__ __forceinline__ f32x4 mfma16(bf16x8 a, bf16x8 b, f32x4 c) {
  return __builtin_amdgcn_mfma_f32_16x16x32_bf16(a, b, c, 0, 0, 0);
}
static __device__ __forceinline__ f32x16 mfma32(bf16x8 a, bf16x8 b, f32x16 c) {
  return __builtin_amdgcn_mfma_f32_32x32x16_bf16(a, b, c, 0, 0, 0);
}
static __device__ __forceinline__ unsigned pk2(float a, float b) {
  union { __bf16 h[2]; unsigned u; } z;
  z.h[0] = (__bf16)a; z.h[1] = (__bf16)b;
  return z.u;
}
static __device__ __forceinline__ void gload_lds16(const bf16* g, bf16* l) {
  __builtin_amdgcn_global_load_lds(
      (const __attribute__((address_space(1))) unsigned int*)g,
      (__attribute__((address_space(3))) unsigned int*)l, 16, 0, 0);
}

// ---------------- elementwise f32 -> bf16 convert ----------------
__global__ __launch_bounds__(256) void cvt_k(const float* __restrict__ in,
                                             bf16* __restrict__ out, int n4) {
  int i = blockIdx.x * 256 + threadIdx.x;
  int stride = gridDim.x * 256;
  for (; i < n4; i += stride) {
    f32x4 v = ((const f32x4*)in)[i];
    bf16x4 o;
    o[0] = (bf16)v[0]; o[1] = (bf16)v[1]; o[2] = (bf16)v[2]; o[3] = (bf16)v[3];
    ((bf16x4*)out)[i] = o;
  }
}

// ---------------- transpose f32 (R,C) -> bf16 (C,R), 64x64 tiles, batched z ----------------
__global__ __launch_bounds__(256) void transpose_k(const float* __restrict__ in,
                                                   bf16* __restrict__ out, int R, int C) {
  __shared__ float tile[64][65];
  const size_t zoff = (size_t)blockIdx.z * R * C;
  in += zoff; out += zoff;
  const int c0 = blockIdx.x * 64, r0 = blockIdx.y * 64;
  const int tx = threadIdx.x & 15, ty = threadIdx.x >> 4;  // 16 x 16
#pragma unroll
  for (int i = 0; i < 4; i++) {
    const int r = i * 16 + ty;
    f32x4 v = *(const f32x4*)(in + (size_t)(r0 + r) * C + c0 + tx * 4);
    *(f32x4*)&tile[r][tx * 4] = v;
  }
  __syncthreads();
#pragma unroll
  for (int i = 0; i < 4; i++) {
    const int rr = i * 16 + ty;  // output row within tile (= source col)
    bf16x4 o;
#pragma unroll
    for (int j = 0; j < 4; j++) o[j] = (bf16)tile[tx * 4 + j][rr];
    *(bf16x4*)(out + (size_t)(c0 + rr) * R + r0 + tx * 4) = o;
  }
}

// ---------------- transpose bf16 v (per bh: (T,HD) -> (HD,T)) ----------------
__global__ __launch_bounds__(256) void transpose_v_k(const bf16* __restrict__ v,
                                                     bf16* __restrict__ vT) {
  __shared__ bf16 tile[32][33];
  int bh = blockIdx.z;
  const bf16* in = v + (size_t)bh * NT * HD_;
  bf16* out = vT + (size_t)bh * HD_ * NT;
  int t0 = blockIdx.x * 32, d0 = blockIdx.y * 32;
  int tx = threadIdx.x, ty = threadIdx.y;
#pragma unroll
  for (int i = 0; i < 4; i++)
    tile[ty + i * 8][tx] = in[(size_t)(t0 + ty + i * 8) * HD_ + d0 + tx];
  __syncthreads();
#pragma unroll
  for (int i = 0; i < 4; i++)
    out[(size_t)(d0 + ty + i * 8) * NT + t0 + tx] = tile[tx][ty + i * 8];
}

// ---------------- rope sin/cos table ----------------
__global__ void rope_tab_k(float* __restrict__ tab) {
  int t = blockIdx.x, i = threadIdx.x;  // 32 threads
  float inv = powf(10000.f, -(float)(2 * i) * (1.f / 64.f));
  float ang = (float)t * inv;
  float s, c;
  sincosf(ang, &s, &c);
  tab[(t * 32 + i) * 2] = s;
  tab[(t * 32 + i) * 2 + 1] = c;
}

// ---------------- layernorm (row of 1024) -> bf16 ----------------
__global__ __launch_bounds__(256) void ln_k(const float* __restrict__ in,
                                            const float* __restrict__ g,
                                            const float* __restrict__ bb,
                                            bf16* __restrict__ outb) {
  const int row = blockIdx.x;
  const float* xr = in + (size_t)row * ND;
  const int tid = threadIdx.x, lane = tid & 63, wid = tid >> 6;
  f32x4 v = ((const f32x4*)xr)[tid];
  float s = v[0] + v[1] + v[2] + v[3];
  float sq = v[0] * v[0] + v[1] * v[1] + v[2] * v[2] + v[3] * v[3];
#pragma unroll
  for (int m = 1; m < 64; m <<= 1) {
    s += __shfl_xor(s, m, 64);
    sq += __shfl_xor(sq, m, 64);
  }
  __shared__ float red[8];
  if (lane == 0) { red[wid] = s; red[4 + wid] = sq; }
  __syncthreads();
  s = red[0] + red[1] + red[2] + red[3];
  sq = red[4] + red[5] + red[6] + red[7];
  float mean = s * (1.f / 1024.f);
  float var = sq * (1.f / 1024.f) - mean * mean;
  float rs = rsqrtf(var + 1e-5f);
#pragma unroll
  for (int c = 0; c < 4; c++) {
    int col = tid * 4 + c;
    float y = (v[c] - mean) * rs * g[col] + bb[col];
    outb[(size_t)row * ND + col] = (bf16)y;
  }
}

// ---------------- fused layernorm + gate (logits, softmax, top2) ----------------
__global__ __launch_bounds__(256) void ln_gate_k(const float* __restrict__ in,
                                                 const float* __restrict__ g,
                                                 const float* __restrict__ bb,
                                                 const float* __restrict__ w_gate,
                                                 float* __restrict__ moein,
                                                 int* __restrict__ idx,
                                                 float* __restrict__ gv) {
  const int row = blockIdx.x;
  const float* xr = in + (size_t)row * ND;
  const int tid = threadIdx.x, lane = tid & 63, wid = tid >> 6;
  f32x4 v = ((const f32x4*)xr)[tid];
  float s = v[0] + v[1] + v[2] + v[3];
  float sq = v[0] * v[0] + v[1] * v[1] + v[2] * v[2] + v[3] * v[3];
#pragma unroll
  for (int m = 1; m < 64; m <<= 1) {
    s += __shfl_xor(s, m, 64);
    sq += __shfl_xor(sq, m, 64);
  }
  __shared__ float red[8];
  if (lane == 0) { red[wid] = s; red[4 + wid] = sq; }
  __syncthreads();
  s = red[0] + red[1] + red[2] + red[3];
  sq = red[4] + red[5] + red[6] + red[7];
  float mean = s * (1.f / 1024.f);
  float var = sq * (1.f / 1024.f) - mean * mean;
  float rs = rsqrtf(var + 1e-5f);
  f32x4 y;
#pragma unroll
  for (int c = 0; c < 4; c++) {
    int col = tid * 4 + c;
    y[c] = (v[c] - mean) * rs * g[col] + bb[col];
  }
  *(f32x4*)(moein + (size_t)row * ND + tid * 4) = y;
  // gate logits: 8 dot products of the normalized row with w_gate rows
  float a[8];
#pragma unroll
  for (int e = 0; e < 8; e++) {
    f32x4 wv = *(const f32x4*)(w_gate + e * ND + tid * 4);
    a[e] = y[0] * wv[0] + y[1] * wv[1] + y[2] * wv[2] + y[3] * wv[3];
  }
#pragma unroll
  for (int e = 0; e < 8; e++)
#pragma unroll
    for (int m = 1; m < 64; m <<= 1) a[e] += __shfl_xor(a[e], m, 64);
  __shared__ float red2[4][8];
  if (lane < 8) red2[wid][lane] = a[lane];
  __syncthreads();
  if (tid == 0) {
    float t[8];
#pragma unroll
    for (int e = 0; e < 8; e++)
      t[e] = red2[0][e] + red2[1][e] + red2[2][e] + red2[3][e];
    float mx = t[0];
#pragma unroll
    for (int e = 1; e < 8; e++) mx = fmaxf(mx, t[e]);
    float p[8], se = 0.f;
#pragma unroll
    for (int e = 0; e < 8; e++) { p[e] = expf(t[e] - mx); se += p[e]; }
    float inv = 1.f / se;
#pragma unroll
    for (int e = 0; e < 8; e++) p[e] *= inv;
    int i1 = 0; float v1 = p[0];
#pragma unroll
    for (int e = 1; e < 8; e++) if (p[e] > v1) { v1 = p[e]; i1 = e; }
    int i2 = -1; float v2 = -1.f;
#pragma unroll
    for (int e = 0; e < 8; e++) if (e != i1 && p[e] > v2) { v2 = p[e]; i2 = e; }
    idx[row * 2] = i1; idx[row * 2 + 1] = i2;
    gv[row * 2] = v1; gv[row * 2 + 1] = v2;
  }
}

// ---------------- GEMM: C(M,N) = A(M,K) * B(N,K)^T, bf16 in, f32 accum ----------------
// STAGE=0: m97 gload_lds 1-phase (linear LDS), right at >=3 blocks/CU.
// STAGE=1: reg-staged 2-DEEP pipelined (named buffers, step-unrolled x2 --
//   rule #20), right at low blocks/CU. Requires nst even (proj 16, GEMM2 32).
// NSPLIT (compile-time): split-K; EPI_STORE writes per-chunk bf16 partials.
// MSWZ: XCD-locality swizzle -- m-tiles sharing one B-panel land on one XCD.
#define EPI_SPLIT_QKV 0
#define EPI_ADD_X 1
#define EPI_BIAS_GELU 2
#define EPI_STORE 3

template <int EPI, int STAGE, bool PAD, int NSPLIT, bool MSWZ>
__global__ __launch_bounds__(256) void gemm_bt_k(
    const bf16* __restrict__ A, const bf16* __restrict__ Bw,
    const int M, const int N, const int K,
    const size_t zA, const size_t zB, const size_t zOut, const size_t zBias,
    const float* __restrict__ bias, const float* __restrict__ Xadd,
    void* __restrict__ Out, bf16* __restrict__ k_out, bf16* __restrict__ v_out) {
  int bx = blockIdx.x, by = blockIdx.y, bz = blockIdx.z;
  if constexpr (MSWZ) {
    const int gx = gridDim.x, gy = gridDim.y;
    int lin = bx + gx * (by + gy * bz);
    int xcd = lin & 7;
    int t = lin >> 3;
    by = t % gy;              // m-tile
    int gq = t / gy;
    int gg = gq * 8 + xcd;    // (n, z) panel id
    bx = gg % gx;
    bz = gg / gx;
  }
  const int z = bz;
  const int ze = z / NSPLIT;
  const int kc = z % NSPLIT;
  const int klen = K / NSPLIT;
  const int kb = kc * klen;
  const int nst = klen / 64;
  const int m0 = by * 128, n0 = bx * 128;
  const int tid = threadIdx.x, lane = tid & 63, wid = tid >> 6;
  const int wm = (wid >> 1) * 64, wn = (wid & 1) * 64;
  const int l15 = lane & 15, ksl = lane >> 4;
  constexpr int LDB = (STAGE == 1 && PAD) ? 72 : 64;
  __shared__ __align__(16) bf16 As[128 * LDB];
  __shared__ __align__(16) bf16 Bs[128 * LDB];
  f32x4 acc[4][4];
#pragma unroll
  for (int i = 0; i < 4; i++)
#pragma unroll
    for (int j = 0; j < 4; j++) acc[i][j] = (f32x4){0.f, 0.f, 0.f, 0.f};

  if constexpr (STAGE == 0) {
    const int lr = lane >> 3, lc = (lane & 7) * 8;
    const bf16* Ag = A + zA * ze + (size_t)(m0 + wid * 32 + lr) * K + kb + lc;
    const bf16* Bg = Bw + zB * ze + (size_t)(n0 + wid * 32 + lr) * K + kb + lc;
    for (int s = 0; s < nst; ++s) {
      __syncthreads();
#pragma unroll
      for (int it = 0; it < 4; it++) {
        gload_lds16(Ag + (size_t)(it * 8) * K + s * 64, &As[(wid * 32 + it * 8) * 64]);
        gload_lds16(Bg + (size_t)(it * 8) * K + s * 64, &Bs[(wid * 32 + it * 8) * 64]);
      }
      __syncthreads();
#pragma unroll
      for (int kk = 0; kk < 2; kk++) {
        bf16x8 af[4], bfr[4];
        const int ko = kk * 32 + ksl * 8;
#pragma unroll
        for (int i = 0; i < 4; i++)
          af[i] = *(const bf16x8*)&As[(wm + i * 16 + l15) * 64 + ko];
#pragma unroll
        for (int j = 0; j < 4; j++)
          bfr[j] = *(const bf16x8*)&Bs[(wn + j * 16 + l15) * 64 + ko];
#pragma unroll
        for (int i = 0; i < 4; i++)
#pragma unroll
          for (int j = 0; j < 4; j++)
            acc[i][j] = mfma16(af[i], bfr[j], acc[i][j]);
      }
    }
  } else {
    // reg-staged 2-deep pipelined: thread covers (row = flat>>3, col = (flat&7)*8)
    const int sr = tid >> 3, sc = (tid & 7) * 8;
    const bf16* Ag = A + zA * ze + (size_t)(m0 + sr) * K + kb + sc;
    const bf16* Bg = Bw + zB * ze + (size_t)(n0 + sr) * K + kb + sc;
    bf16x8 avA[4], bvA[4], avB[4], bvB[4];
#pragma unroll
    for (int it = 0; it < 4; it++) {
      avA[it] = *(const bf16x8*)(Ag + (size_t)(it * 32) * K);
      bvA[it] = *(const bf16x8*)(Bg + (size_t)(it * 32) * K);
    }
#pragma unroll
    for (int it = 0; it < 4; it++) {
      avB[it] = *(const bf16x8*)(Ag + (size_t)(it * 32) * K + 64);
      bvB[it] = *(const bf16x8*)(Bg + (size_t)(it * 32) * K + 64);
    }
    auto compute = [&]() {
#pragma unroll
      for (int kk = 0; kk < 2; kk++) {
        bf16x8 af[4], bfr[4];
        const int ko = kk * 32 + ksl * 8;
#pragma unroll
        for (int i = 0; i < 4; i++)
          af[i] = *(const bf16x8*)&As[(wm + i * 16 + l15) * LDB + ko];
#pragma unroll
        for (int j = 0; j < 4; j++)
          bfr[j] = *(const bf16x8*)&Bs[(wn + j * 16 + l15) * LDB + ko];
#pragma unroll
        for (int i = 0; i < 4; i++)
#pragma unroll
          for (int j = 0; j < 4; j++)
            acc[i][j] = mfma16(af[i], bfr[j], acc[i][j]);
      }
    };
    for (int s = 0; s < nst; s += 2) {
      // even step: buffer A holds tile s
      __syncthreads();  // previous step's LDS reads done
#pragma unroll
      for (int it = 0; it < 4; it++) {
        *(bf16x8*)&As[(sr + it * 32) * LDB + sc] = avA[it];
        *(bf16x8*)&Bs[(sr + it * 32) * LDB + sc] = bvA[it];
      }
      __syncthreads();  // tile s visible
      if (s + 2 < nst) {  // issue loads for tile s+2; ~2 steps to land
#pragma unroll
        for (int it = 0; it < 4; it++) {
          avA[it] = *(const bf16x8*)(Ag + (size_t)(it * 32) * K + (s + 2) * 64);
          bvA[it] = *(const bf16x8*)(Bg + (size_t)(it * 32) * K + (s + 2) * 64);
        }
      }
      compute();
      // odd step: buffer B holds tile s+1
      __syncthreads();
#pragma unroll
      for (int it = 0; it < 4; it++) {
        *(bf16x8*)&As[(sr + it * 32) * LDB + sc] = avB[it];
        *(bf16x8*)&Bs[(sr + it * 32) * LDB + sc] = bvB[it];
      }
      __syncthreads();
      if (s + 3 < nst) {
#pragma unroll
        for (int it = 0; it < 4; it++) {
          avB[it] = *(const bf16x8*)(Ag + (size_t)(it * 32) * K + (s + 3) * 64);
          bvB[it] = *(const bf16x8*)(Bg + (size_t)(it * 32) * K + (s + 3) * 64);
        }
      }
      compute();
    }
  }

#pragma unroll
  for (int i = 0; i < 4; i++) {
#pragma unroll
    for (int j = 0; j < 4; j++) {
      const int mb = m0 + wm + i * 16 + ksl * 4;
      const int nc = n0 + wn + j * 16 + l15;
#pragma unroll
      for (int r = 0; r < 4; r++) {
        const int mr = mb + r;
        float vacc = acc[i][j][r];
        if constexpr (EPI == EPI_SPLIT_QKV) {
          const int h = nc / 192;
          const int rr = nc - h * 192;
          const int which = rr >> 6;
          const int d = rr & 63;
          const int b = mr >> 11, t = mr & 2047;
          bf16* dst = (which == 0) ? (bf16*)Out : (which == 1 ? k_out : v_out);
          dst[(((size_t)(b * NH + h)) * NT + t) * HD_ + d] = (bf16)vacc;
        } else if constexpr (EPI == EPI_ADD_X) {
          ((float*)Out)[(size_t)mr * N + nc] = vacc + Xadd[(size_t)mr * N + nc];
        } else if constexpr (EPI == EPI_BIAS_GELU) {
          // tanh-gelu via RAW HW builtins (v_exp_f32 + v_rcp_f32, no libm
          // range-check bloat -- the r11/r13 VGPR regression came from
          // libm exp2f, not the formula). ~7 VALU ops vs erff's ~25.
          // |err| vs exact erf-gelu <= ~3e-3 in h -> ~4e-3 in out (thr 0.1).
          float x = vacc + bias[zBias * ze + nc];
          float u2 = x * (2.3020882f + 0.10294772f * x * x);
          float gl = x * __builtin_amdgcn_rcpf(1.f + __builtin_amdgcn_exp2f(-u2));
          ((bf16*)Out)[zOut * ze + (size_t)mr * N + nc] = (bf16)gl;
        } else {  // EPI_STORE: per-K-chunk bf16 partial (chunk stride = zOut*NE)
          ((bf16*)Out)[((size_t)kc * NE + ze) * zOut + (size_t)mr * N + nc] = (bf16)vacc;
        }
      }
    }
  }
}

// ---------------- rope apply (in-place on q,k); q also scaled by 0.125*log2(e) ----------------
__global__ __launch_bounds__(256) void rope_k(bf16* __restrict__ q, bf16* __restrict__ k,
                                              const float* __restrict__ tab) {
  const int bh = blockIdx.y;
  const int t = blockIdx.x * 4 + (threadIdx.x >> 6);
  const int d = threadIdx.x & 63;
  const size_t row = ((size_t)bh * NT + t) * HD_;
  const int i = d & 31;
  const float sn = tab[(t * 32 + i) * 2], cs = tab[(t * 32 + i) * 2 + 1];
  {
    float a = (float)q[row + d];
    float b2 = (float)q[row + (d ^ 32)];
    float o = (d < 32) ? (a * cs - b2 * sn) : (b2 * sn + a * cs);
    q[row + d] = (bf16)(o * 0.18033688011112042f);  // 0.125 * log2(e)
  }
  {
    float a = (float)k[row + d];
    float b2 = (float)k[row + (d ^ 32)];
    float o = (d < 32) ? (a * cs - b2 * sn) : (b2 * sn + a * cs);
    k[row + d] = (bf16)o;
  }
}

// ---------------- flash attention: swapped 32x32 MFMA, in-register softmax ----------------
__global__ __launch_bounds__(256) void attn_k(const bf16* __restrict__ q,
                                              const bf16* __restrict__ k,
                                              const bf16* __restrict__ vT,
                                              bf16* __restrict__ attn_out) {
  __shared__ __align__(16) bf16 Kt[64 * 64];
  __shared__ __align__(16) bf16 Vt[64 * 64];
  const int bid = blockIdx.x;
  const int bh = bid & 31;
  const int ti = (bid >> 5) & 7;
  const int qt = (bid >> 8) ? (15 - ti) : ti;  // causal balance: CU pairs (t,15-t)
  const int q0 = qt * 128;
  const int tid = threadIdx.x, lane = tid & 63, wid = tid >> 6;
  const int l31 = lane & 31, hi = lane >> 5;
  const int q0w = q0 + wid * 32;
  const int qrow = q0w + l31;
  const size_t base = (size_t)bh * (NT * HD_);
  const size_t baseT = (size_t)bh * (HD_ * NT);

  bf16x8 qf[4];
#pragma unroll
  for (int ks = 0; ks < 4; ks++)
    qf[ks] = *(const bf16x8*)(q + base + (size_t)qrow * HD_ + ks * 16 + hi * 8);

  f32x16 ot0, ot1;
#pragma unroll
  for (int r = 0; r < 16; r++) { ot0[r] = 0.f; ot1[r] = 0.f; }
  float m2 = -1e30f, l = 0.f;

  const int ntiles = qt * 2 + 2;
  const int swz = (l31 & 7);
  const int strow = tid >> 3, stc = tid & 7;
  const int cw0 = ((stc ^ (strow & 7)) * 8);
  bf16x8 kr[2], vr[2];
#pragma unroll
  for (int rr = 0; rr < 2; rr++) {  // preload tile 0
    kr[rr] = *(const bf16x8*)(k + base + (size_t)(strow + rr * 32) * HD_ + stc * 8);
    vr[rr] = *(const bf16x8*)(vT + baseT + (size_t)(strow + rr * 32) * NT + stc * 8);
  }

  for (int t = 0; t < ntiles; t++) {
    const int kv0 = t * 64;
    __syncthreads();  // previous tile's LDS reads done
#pragma unroll
    for (int rr = 0; rr < 2; rr++) {
      *(bf16x8*)&Kt[(strow + rr * 32) * 64 + cw0] = kr[rr];
      *(bf16x8*)&Vt[(strow + rr * 32) * 64 + cw0] = vr[rr];
    }
    __syncthreads();  // tile visible
    if (t + 1 < ntiles) {  // issue next-tile loads; hide under compute
      const int kn = kv0 + 64;
#pragma unroll
      for (int rr = 0; rr < 2; rr++) {
        kr[rr] = *(const bf16x8*)(k + base + (size_t)(kn + strow + rr * 32) * HD_ + stc * 8);
        vr[rr] = *(const bf16x8*)(vT + baseT + (size_t)(strow + rr * 32) * NT + kn + stc * 8);
      }
    }
    if (kv0 > q0w + 31) continue;

    f32x16 s0, s1;
#pragma unroll
    for (int r = 0; r < 16; r++) { s0[r] = 0.f; s1[r] = 0.f; }
#pragma unroll
    for (int ks = 0; ks < 4; ks++) {
      const int cw = (((ks * 2 + hi) ^ swz) * 8);
      bf16x8 ka0 = *(const bf16x8*)&Kt[l31 * 64 + cw];
      bf16x8 ka1 = *(const bf16x8*)&Kt[(l31 + 32) * 64 + cw];
      s0 = mfma32(ka0, qf[ks], s0);
      s1 = mfma32(ka1, qf[ks], s1);
    }

    float p[32];
#pragma unroll
    for (int r = 0; r < 16; r++) { p[r] = s0[r]; p[16 + r] = s1[r]; }
    if (kv0 + 63 > q0w) {  // diagonal tile: causal mask
#pragma unroll
      for (int sub = 0; sub < 2; sub++)
#pragma unroll
        for (int r = 0; r < 16; r++) {
          int kvg = kv0 + sub * 32 + (r & 3) + 8 * (r >> 2) + 4 * hi;
          if (kvg > qrow) p[sub * 16 + r] = -1e30f;
        }
    }
    float tm = p[0];
#pragma unroll
    for (int r = 1; r < 32; r++) tm = fmaxf(tm, p[r]);
    tm = fmaxf(tm, __shfl_xor(tm, 32, 64));
    if (!__all(tm <= m2 + 8.f)) {  // defer-max
      float mn = fmaxf(m2, tm);
      float sf = __builtin_amdgcn_exp2f(m2 - mn);
      m2 = mn;
      l *= sf;
#pragma unroll
      for (int r = 0; r < 16; r++) { ot0[r] *= sf; ot1[r] *= sf; }
    }
    float ts = 0.f;
#pragma unroll
    for (int r = 0; r < 32; r++) { p[r] = __builtin_amdgcn_exp2f(p[r] - m2); ts += p[r]; }
    ts += __shfl_xor(ts, 32, 64);
    l += ts;

#pragma unroll
    for (int ks = 0; ks < 4; ks++) {
      const int i0 = (ks >> 1) * 16 + (ks & 1) * 8;
      unsigned Aw = pk2(p[i0 + 0], p[i0 + 1]);
      unsigned Bw = pk2(p[i0 + 2], p[i0 + 3]);
      unsigned Cw = pk2(p[i0 + 4], p[i0 + 5]);
      unsigned Dw = pk2(p[i0 + 6], p[i0 + 7]);
      unsigned xA = (unsigned)__shfl_xor((int)Aw, 32, 64);
      unsigned xB = (unsigned)__shfl_xor((int)Bw, 32, 64);
      unsigned xC = (unsigned)__shfl_xor((int)Cw, 32, 64);
      unsigned xD = (unsigned)__shfl_xor((int)Dw, 32, 64);
      union { unsigned u[4]; bf16x8 v; } pa;
      pa.u[0] = hi ? xC : Aw;
      pa.u[1] = hi ? xD : Bw;
      pa.u[2] = hi ? Cw : xA;
      pa.u[3] = hi ? Dw : xB;
      const int cw = (((ks * 2 + hi) ^ swz) * 8);
      bf16x8 va0 = *(const bf16x8*)&Vt[l31 * 64 + cw];
      bf16x8 va1 = *(const bf16x8*)&Vt[(l31 + 32) * 64 + cw];
      ot0 = mfma32(va0, pa.v, ot0);
      ot1 = mfma32(va1, pa.v, ot1);
    }
  }

  const int b = bh >> 4, h = bh & 15;
  const float inv = 1.f / l;
  const size_t orow = ((size_t)(b * NT + qrow)) * ND + h * 64;
#pragma unroll
  for (int g = 0; g < 4; g++) {
    bf16x4 w0, w1;
#pragma unroll
    for (int c = 0; c < 4; c++) {
      w0[c] = (bf16)(ot0[g * 4 + c] * inv);
      w1[c] = (bf16)(ot1[g * 4 + c] * inv);
    }
    *(bf16x4*)(attn_out + orow + g * 8 + 4 * hi) = w0;
    *(bf16x4*)(attn_out + orow + 32 + g * 8 + 4 * hi) = w1;
  }
}

// ---------------- capacity scan (single wave, token order, batched loads) ----------------
__global__ void scan_k(const int* __restrict__ idx, int* __restrict__ slot,
                       int* __restrict__ kept) {
  const int lane = threadIdx.x;
  int base[8];
#pragma unroll
  for (int e = 0; e < 8; e++) base[e] = 0;
  const unsigned long long lm = (lane == 63) ? ~0ull : ((1ull << (lane + 1)) - 1);
  for (int cb = 0; cb < 64; cb += 8) {
    int2 ev[8];  // batch 8 chunks' (e0,e1) -- loads issue together, latency amortized
#pragma unroll
    for (int u = 0; u < 8; u++)
      ev[u] = ((const int2*)idx)[(cb + u) * 64 + lane];
#pragma unroll
    for (int u = 0; u < 8; u++) {
      const int n = (cb + u) * 64 + lane;
      const int e0 = ev[u].x, e1 = ev[u].y;
      int s0 = 0, s1 = 0;
#pragma unroll
      for (int e = 0; e < 8; e++) {
        unsigned long long m0 = __ballot(e0 == e);
        unsigned long long m1 = __ballot(e1 == e);
        unsigned long long m = m0 | m1;
        int pref = __popcll(m & lm);
        if (e0 == e) s0 = base[e] + pref - 1;
        if (e1 == e) s1 = base[e] + pref - 1;
        base[e] += __popcll(m);
      }
      slot[n * 2] = s0; slot[n * 2 + 1] = s1;
      kept[n * 2] = (s0 < NCAP) ? 1 : 0;
      kept[n * 2 + 1] = (s1 < NCAP) ? 1 : 0;
    }
  }
}

// ---------------- scatter tokens into expert buffers ----------------
__global__ __launch_bounds__(64) void scatter_k(const float* __restrict__ moe_in,
                                                const int* __restrict__ idx,
                                                const int* __restrict__ slot,
                                                const int* __restrict__ kept,
                                                bf16* __restrict__ buf) {
  const int a = blockIdx.x;
  if (!kept[a]) return;
  const int n = a >> 1;
  const int e = idx[a], s = slot[a];
  const float* src = moe_in + (size_t)n * ND;
  bf16* dst = buf + ((size_t)e * NCAP + s) * ND;
  for (int c = threadIdx.x * 4; c < 1024; c += 256) {
    f32x4 v = *(const f32x4*)(src + c);
    bf16x4 o;
    o[0] = (bf16)v[0]; o[1] = (bf16)v[1]; o[2] = (bf16)v[2]; o[3] = (bf16)v[3];
    *(bf16x4*)(dst + c) = o;
  }
}

// ---------------- gather expert outputs (2 K-partials + b2, gate) + residual ----------------
__global__ __launch_bounds__(256) void gather_k(const float* __restrict__ h,
                                                const bf16* __restrict__ eout,
                                                const int* __restrict__ idx,
                                                const int* __restrict__ slot,
                                                const int* __restrict__ kept,
                                                const float* __restrict__ gv,
                                                const float* __restrict__ b2,
                                                float* __restrict__ out) {
  const size_t PS = (size_t)NE * NCAP * ND;  // partial stride
  const int n = blockIdx.x;
  const int k0 = kept[n * 2], k1 = kept[n * 2 + 1];
  const int i0 = idx[n * 2], i1 = idx[n * 2 + 1];
  const float g0 = k0 ? gv[n * 2] : 0.f;
  const float g1 = k1 ? gv[n * 2 + 1] : 0.f;
  const size_t r0 = k0 ? ((size_t)i0 * NCAP + slot[n * 2]) * ND : 0;
  const size_t r1 = k1 ? ((size_t)i1 * NCAP + slot[n * 2 + 1]) * ND : 0;
  const int c = threadIdx.x * 4;
  f32x4 o = *(const f32x4*)(h + (size_t)n * ND + c);
  if (k0) {
    bf16x4 ea = *(const bf16x4*)(eout + r0 + c);
    bf16x4 eb = *(const bf16x4*)(eout + PS + r0 + c);
    f32x4 bb = *(const f32x4*)(b2 + i0 * ND + c);
#pragma unroll
    for (int cc = 0; cc < 4; cc++)
      o[cc] += g0 * ((float)ea[cc] + (float)eb[cc] + bb[cc]);
  }
  if (k1) {
    bf16x4 ea = *(const bf16x4*)(eout + r1 + c);
    bf16x4 eb = *(const bf16x4*)(eout + PS + r1 + c);
    f32x4 bb = *(const f32x4*)(b2 + i1 * ND + c);
#pragma unroll
    for (int cc = 0; cc < 4; cc++)
      o[cc] += g1 * ((float)ea[cc] + (float)eb[cc] + bb[cc]);
  }
  *(f32x4*)(out + (size_t)n * ND + c) = o;
}

// ---------------- launcher ----------------
extern "C" void kernel_launch(void* const* d_in, const int* in_sizes, int n_in,
                              void* d_out, int out_size, void* d_ws, size_t ws_size,
                              hipStream_t stream) {
  (void)in_sizes; (void)n_in; (void)out_size;
  const float* x      = (const float*)d_in[0];
  const float* ln1_g  = (const float*)d_in[1];
  const float* ln1_b  = (const float*)d_in[2];
  const float* w_qkv  = (const float*)d_in[3];
  const float* w_proj = (const float*)d_in[4];
  const float* ln2_g  = (const float*)d_in[5];
  const float* ln2_b  = (const float*)d_in[6];
  const float* w_gate = (const float*)d_in[7];
  const float* w1     = (const float*)d_in[8];
  const float* b1     = (const float*)d_in[9];
  const float* w2     = (const float*)d_in[10];
  const float* b2     = (const float*)d_in[11];
  float* out = (float*)d_out;

  char* ws = (char*)d_ws;
  size_t off = 0;
  auto alloc = [&](size_t bytes) -> char* {
    char* p = ws + off;
    off += (bytes + 255) & ~(size_t)255;
    return p;
  };
  bf16* w1t    = (bf16*)alloc((size_t)NE * NDFF * ND * 2);     // 67.1 MB
  bf16* w2t    = (bf16*)alloc((size_t)NE * ND * NDFF * 2);     // 67.1 MB
  bf16* wqkvb  = (bf16*)alloc((size_t)3 * ND * ND * 2);        // 6.29 MB
  bf16* wprojb = (bf16*)alloc((size_t)ND * ND * 2);            // 2.10 MB
  float* hbufr = (float*)alloc((size_t)NTOK * ND * 4);         // h, 16.78 MB
  float* moein = (float*)alloc((size_t)NTOK * ND * 4);         // 16.78 MB
  float* ropet = (float*)alloc((size_t)NT * 32 * 2 * 4);       // 0.52 MB
  int*   idx   = (int*)alloc((size_t)NTOK * 2 * 4);
  int*   slot  = (int*)alloc((size_t)NTOK * 2 * 4);
  int*   kept  = (int*)alloc((size_t)NTOK * 2 * 4);
  float* gv    = (float*)alloc((size_t)NTOK * 2 * 4);
  char*  S     = alloc((size_t)62914560);                      // 62.9 MB shared region
  if (off > ws_size) return;

  // phase A layout (attention)
  const size_t MB8 = (size_t)8388608;
  bf16* xn    = (bf16*)(S);
  bf16* qp    = (bf16*)(S + MB8);
  bf16* kp    = (bf16*)(S + 2 * MB8);
  bf16* vp    = (bf16*)(S + 3 * MB8);
  bf16* attnp = (bf16*)(S + 4 * MB8);
  bf16* vTp   = (bf16*)(S);                       // alias xn (dead after qkv gemm)
  // phase B layout (MoE): hbuf [0,41.9M), buf [41.9,52.4M),
  // eout (2 bf16 partials, 21 MB) [41.9,62.9M) -- aliases buf after gemm1.
  bf16* hbuf  = (bf16*)(S);
  bf16* buf   = (bf16*)(S + (size_t)41943040);
  bf16* eout  = (bf16*)(S + (size_t)41943040);

  dim3 tb(32, 8);
  cvt_k<<<2048, 256, 0, stream>>>(w_qkv, wqkvb, 3 * ND * ND / 4);
  cvt_k<<<1024, 256, 0, stream>>>(w_proj, wprojb, ND * ND / 4);
  transpose_k<<<dim3(NDFF / 64, ND / 64, NE), 256, 0, stream>>>(w1, w1t, ND, NDFF);
  transpose_k<<<dim3(ND / 64, NDFF / 64, NE), 256, 0, stream>>>(w2, w2t, NDFF, ND);
  rope_tab_k<<<NT, 32, 0, stream>>>(ropet);
  ln_k<<<NTOK, 256, 0, stream>>>(x, ln1_g, ln1_b, xn);
  // qkv: grid 768 (3 blocks/CU) -> gload 1-phase
  gemm_bt_k<EPI_SPLIT_QKV, 0, false, 1, false>
      <<<dim3(3 * ND / 128, NTOK / 128, 1), 256, 0, stream>>>(
      xn, wqkvb, NTOK, 3 * ND, ND, 0, 0, 0, 0, nullptr, nullptr, qp, kp, vp);
  transpose_v_k<<<dim3(NT / 32, HD_ / 32, NB * NH), tb, 0, stream>>>(vp, vTp);
  rope_k<<<dim3(NT / 4, NB * NH), 256, 0, stream>>>(qp, kp, ropet);
  attn_k<<<512, 256, 0, stream>>>(qp, kp, vTp, attnp);
  // proj: grid 256 (1 block/CU) -> reg-staged 2-deep pipelined, padded LDS
  gemm_bt_k<EPI_ADD_X, 1, true, 1, false>
      <<<dim3(ND / 128, NTOK / 128, 1), 256, 0, stream>>>(
      attnp, wprojb, NTOK, ND, ND, 0, 0, 0, 0, nullptr, x, hbufr, nullptr, nullptr);
  // fused ln2 + gating
  ln_gate_k<<<NTOK, 256, 0, stream>>>(hbufr, ln2_g, ln2_b, w_gate, moein, idx, gv);
  scan_k<<<1, 64, 0, stream>>>(idx, slot, kept);
  scatter_k<<<NTOK * 2, 64, 0, stream>>>(moein, idx, slot, kept, buf);
  // moe GEMM1: grid 1280 (5 blocks/CU) -> gload 1-phase, builtin-gelu, XCD swizzle
  gemm_bt_k<EPI_BIAS_GELU, 0, false, 1, true>
      <<<dim3(NDFF / 128, NCAP / 128, NE), 256, 0, stream>>>(
      buf, w1t, NCAP, NDFF, ND, (size_t)NCAP * ND, (size_t)NDFF * ND,
      (size_t)NCAP * NDFF, NDFF, b1, nullptr, hbuf, nullptr, nullptr);
  // moe GEMM2: split-K=2 (grid 640), reg-staged 2-deep, bf16 partials, XCD swizzle
  gemm_bt_k<EPI_STORE, 1, true, 2, true>
      <<<dim3(ND / 128, NCAP / 128, NE * 2), 256, 0, stream>>>(
      hbuf, w2t, NCAP, ND, NDFF, (size_t)NCAP * NDFF, (size_t)ND * NDFF,
      (size_t)NCAP * ND, 0, nullptr, nullptr, eout, nullptr, nullptr);
  gather_k<<<NTOK, 256, 0, stream>>>(hbufr, eout, idx, slot, kept, gv, b2, out);
}

// Round 17
// 425.916 us; speedup vs baseline: 1.0220x; 1.0220x over previous
//
#include <hip/hip_runtime.h>
#include <hip/hip_bf16.h>

typedef __bf16 bf16;
typedef __attribute__((ext_vector_type(8))) __bf16 bf16x8;
typedef __attribute__((ext_vector_type(4))) __bf16 bf16x4;
typedef __attribute__((ext_vector_type(4))) float f32x4;
typedef __attribute__((ext_vector_type(16))) float f32x16;

#define NB 2
#define NT 2048
#define ND 1024
#define NH 16
#define HD_ 64
#define NE 8
#define NCAP 640
#define NTOK 4096
#define NDFF 4096

static __device__ __forceinline__ f32x4 mfma16(bf16x8 a, bf16x8 b, f32x4 c) {
  return __builtin_amdgcn_mfma_f32_16x16x32_bf16(a, b, c, 0, 0, 0);
}
static __device__ __forceinline__ f32x16 mfma32(bf16x8 a, bf16x8 b, f32x16 c) {
  return __builtin_amdgcn_mfma_f32_32x32x16_bf16(a, b, c, 0, 0, 0);
}
static __device__ __forceinline__ unsigned pk2(float a, float b) {
  union { __bf16 h[2]; unsigned u; } z;
  z.h[0] = (__bf16)a; z.h[1] = (__bf16)b;
  return z.u;
}
static __device__ __forceinline__ void gload_lds16(const bf16* g, bf16* l) {
  __builtin_amdgcn_global_load_lds(
      (const __attribute__((address_space(1))) unsigned int*)g,
      (__attribute__((address_space(3))) unsigned int*)l, 16, 0, 0);
}

// ---------------- elementwise f32 -> bf16 convert ----------------
__global__ __launch_bounds__(256) void cvt_k(const float* __restrict__ in,
                                             bf16* __restrict__ out, int n4) {
  int i = blockIdx.x * 256 + threadIdx.x;
  int stride = gridDim.x * 256;
  for (; i < n4; i += stride) {
    f32x4 v = ((const f32x4*)in)[i];
    bf16x4 o;
    o[0] = (bf16)v[0]; o[1] = (bf16)v[1]; o[2] = (bf16)v[2]; o[3] = (bf16)v[3];
    ((bf16x4*)out)[i] = o;
  }
}

// ---------------- transpose f32 (R,C) -> bf16 (C,R), 64x64 tiles, batched z ----------------
__global__ __launch_bounds__(256) void transpose_k(const float* __restrict__ in,
                                                   bf16* __restrict__ out, int R, int C) {
  __shared__ float tile[64][65];
  const size_t zoff = (size_t)blockIdx.z * R * C;
  in += zoff; out += zoff;
  const int c0 = blockIdx.x * 64, r0 = blockIdx.y * 64;
  const int tx = threadIdx.x & 15, ty = threadIdx.x >> 4;  // 16 x 16
#pragma unroll
  for (int i = 0; i < 4; i++) {
    const int r = i * 16 + ty;
    f32x4 v = *(const f32x4*)(in + (size_t)(r0 + r) * C + c0 + tx * 4);
    *(f32x4*)&tile[r][tx * 4] = v;
  }
  __syncthreads();
#pragma unroll
  for (int i = 0; i < 4; i++) {
    const int rr = i * 16 + ty;  // output row within tile (= source col)
    bf16x4 o;
#pragma unroll
    for (int j = 0; j < 4; j++) o[j] = (bf16)tile[tx * 4 + j][rr];
    *(bf16x4*)(out + (size_t)(c0 + rr) * R + r0 + tx * 4) = o;
  }
}

// ---------------- transpose bf16 v (per bh: (T,HD) -> (HD,T)) ----------------
__global__ __launch_bounds__(256) void transpose_v_k(const bf16* __restrict__ v,
                                                     bf16* __restrict__ vT) {
  __shared__ bf16 tile[32][33];
  int bh = blockIdx.z;
  const bf16* in = v + (size_t)bh * NT * HD_;
  bf16* out = vT + (size_t)bh * HD_ * NT;
  int t0 = blockIdx.x * 32, d0 = blockIdx.y * 32;
  int tx = threadIdx.x, ty = threadIdx.y;
#pragma unroll
  for (int i = 0; i < 4; i++)
    tile[ty + i * 8][tx] = in[(size_t)(t0 + ty + i * 8) * HD_ + d0 + tx];
  __syncthreads();
#pragma unroll
  for (int i = 0; i < 4; i++)
    out[(size_t)(d0 + ty + i * 8) * NT + t0 + tx] = tile[tx][ty + i * 8];
}

// ---------------- rope sin/cos table ----------------
__global__ void rope_tab_k(float* __restrict__ tab) {
  int t = blockIdx.x, i = threadIdx.x;  // 32 threads
  float inv = powf(10000.f, -(float)(2 * i) * (1.f / 64.f));
  float ang = (float)t * inv;
  float s, c;
  sincosf(ang, &s, &c);
  tab[(t * 32 + i) * 2] = s;
  tab[(t * 32 + i) * 2 + 1] = c;
}

// ---------------- layernorm (row of 1024) -> bf16 ----------------
__global__ __launch_bounds__(256) void ln_k(const float* __restrict__ in,
                                            const float* __restrict__ g,
                                            const float* __restrict__ bb,
                                            bf16* __restrict__ outb) {
  const int row = blockIdx.x;
  const float* xr = in + (size_t)row * ND;
  const int tid = threadIdx.x, lane = tid & 63, wid = tid >> 6;
  f32x4 v = ((const f32x4*)xr)[tid];
  float s = v[0] + v[1] + v[2] + v[3];
  float sq = v[0] * v[0] + v[1] * v[1] + v[2] * v[2] + v[3] * v[3];
#pragma unroll
  for (int m = 1; m < 64; m <<= 1) {
    s += __shfl_xor(s, m, 64);
    sq += __shfl_xor(sq, m, 64);
  }
  __shared__ float red[8];
  if (lane == 0) { red[wid] = s; red[4 + wid] = sq; }
  __syncthreads();
  s = red[0] + red[1] + red[2] + red[3];
  sq = red[4] + red[5] + red[6] + red[7];
  float mean = s * (1.f / 1024.f);
  float var = sq * (1.f / 1024.f) - mean * mean;
  float rs = rsqrtf(var + 1e-5f);
#pragma unroll
  for (int c = 0; c < 4; c++) {
    int col = tid * 4 + c;
    float y = (v[c] - mean) * rs * g[col] + bb[col];
    outb[(size_t)row * ND + col] = (bf16)y;
  }
}

// ---------------- fused layernorm + gate (logits, softmax, top2) ----------------
__global__ __launch_bounds__(256) void ln_gate_k(const float* __restrict__ in,
                                                 const float* __restrict__ g,
                                                 const float* __restrict__ bb,
                                                 const float* __restrict__ w_gate,
                                                 float* __restrict__ moein,
                                                 int* __restrict__ idx,
                                                 float* __restrict__ gv) {
  const int row = blockIdx.x;
  const float* xr = in + (size_t)row * ND;
  const int tid = threadIdx.x, lane = tid & 63, wid = tid >> 6;
  f32x4 v = ((const f32x4*)xr)[tid];
  float s = v[0] + v[1] + v[2] + v[3];
  float sq = v[0] * v[0] + v[1] * v[1] + v[2] * v[2] + v[3] * v[3];
#pragma unroll
  for (int m = 1; m < 64; m <<= 1) {
    s += __shfl_xor(s, m, 64);
    sq += __shfl_xor(sq, m, 64);
  }
  __shared__ float red[8];
  if (lane == 0) { red[wid] = s; red[4 + wid] = sq; }
  __syncthreads();
  s = red[0] + red[1] + red[2] + red[3];
  sq = red[4] + red[5] + red[6] + red[7];
  float mean = s * (1.f / 1024.f);
  float var = sq * (1.f / 1024.f) - mean * mean;
  float rs = rsqrtf(var + 1e-5f);
  f32x4 y;
#pragma unroll
  for (int c = 0; c < 4; c++) {
    int col = tid * 4 + c;
    y[c] = (v[c] - mean) * rs * g[col] + bb[col];
  }
  *(f32x4*)(moein + (size_t)row * ND + tid * 4) = y;
  // gate logits: 8 dot products of the normalized row with w_gate rows
  float a[8];
#pragma unroll
  for (int e = 0; e < 8; e++) {
    f32x4 wv = *(const f32x4*)(w_gate + e * ND + tid * 4);
    a[e] = y[0] * wv[0] + y[1] * wv[1] + y[2] * wv[2] + y[3] * wv[3];
  }
#pragma unroll
  for (int e = 0; e < 8; e++)
#pragma unroll
    for (int m = 1; m < 64; m <<= 1) a[e] += __shfl_xor(a[e], m, 64);
  __shared__ float red2[4][8];
  if (lane < 8) red2[wid][lane] = a[lane];
  __syncthreads();
  if (tid == 0) {
    float t[8];
#pragma unroll
    for (int e = 0; e < 8; e++)
      t[e] = red2[0][e] + red2[1][e] + red2[2][e] + red2[3][e];
    float mx = t[0];
#pragma unroll
    for (int e = 1; e < 8; e++) mx = fmaxf(mx, t[e]);
    float p[8], se = 0.f;
#pragma unroll
    for (int e = 0; e < 8; e++) { p[e] = expf(t[e] - mx); se += p[e]; }
    float inv = 1.f / se;
#pragma unroll
    for (int e = 0; e < 8; e++) p[e] *= inv;
    int i1 = 0; float v1 = p[0];
#pragma unroll
    for (int e = 1; e < 8; e++) if (p[e] > v1) { v1 = p[e]; i1 = e; }
    int i2 = -1; float v2 = -1.f;
#pragma unroll
    for (int e = 0; e < 8; e++) if (e != i1 && p[e] > v2) { v2 = p[e]; i2 = e; }
    idx[row * 2] = i1; idx[row * 2 + 1] = i2;
    gv[row * 2] = v1; gv[row * 2 + 1] = v2;
  }
}

// ---------------- GEMM: C(M,N) = A(M,K) * B(N,K)^T, bf16 in, f32 accum ----------------
// STAGE=0: m97 gload_lds 1-phase (linear LDS), right at >=3 blocks/CU.
// STAGE=1: reg-staged 2-DEEP pipelined (named buffers, step-unrolled x2 --
//   rule #20), right at low blocks/CU. Requires nst even (proj 16, GEMM2 32).
// NSPLIT (compile-time): split-K; EPI_STORE writes per-chunk bf16 partials.
// MSWZ: XCD-locality swizzle -- m-tiles sharing one B-panel land on one XCD.
#define EPI_SPLIT_QKV 0
#define EPI_ADD_X 1
#define EPI_BIAS_GELU 2
#define EPI_STORE 3

template <int EPI, int STAGE, bool PAD, int NSPLIT, bool MSWZ>
__global__ __launch_bounds__(256) void gemm_bt_k(
    const bf16* __restrict__ A, const bf16* __restrict__ Bw,
    const int M, const int N, const int K,
    const size_t zA, const size_t zB, const size_t zOut, const size_t zBias,
    const float* __restrict__ bias, const float* __restrict__ Xadd,
    void* __restrict__ Out, bf16* __restrict__ k_out, bf16* __restrict__ v_out) {
  int bx = blockIdx.x, by = blockIdx.y, bz = blockIdx.z;
  if constexpr (MSWZ) {
    const int gx = gridDim.x, gy = gridDim.y;
    int lin = bx + gx * (by + gy * bz);
    int xcd = lin & 7;
    int t = lin >> 3;
    by = t % gy;              // m-tile
    int gq = t / gy;
    int gg = gq * 8 + xcd;    // (n, z) panel id
    bx = gg % gx;
    bz = gg / gx;
  }
  const int z = bz;
  const int ze = z / NSPLIT;
  const int kc = z % NSPLIT;
  const int klen = K / NSPLIT;
  const int kb = kc * klen;
  const int nst = klen / 64;
  const int m0 = by * 128, n0 = bx * 128;
  const int tid = threadIdx.x, lane = tid & 63, wid = tid >> 6;
  const int wm = (wid >> 1) * 64, wn = (wid & 1) * 64;
  const int l15 = lane & 15, ksl = lane >> 4;
  constexpr int LDB = (STAGE == 1 && PAD) ? 72 : 64;
  __shared__ __align__(16) bf16 As[128 * LDB];
  __shared__ __align__(16) bf16 Bs[128 * LDB];
  f32x4 acc[4][4];
#pragma unroll
  for (int i = 0; i < 4; i++)
#pragma unroll
    for (int j = 0; j < 4; j++) acc[i][j] = (f32x4){0.f, 0.f, 0.f, 0.f};

  if constexpr (STAGE == 0) {
    const int lr = lane >> 3, lc = (lane & 7) * 8;
    const bf16* Ag = A + zA * ze + (size_t)(m0 + wid * 32 + lr) * K + kb + lc;
    const bf16* Bg = Bw + zB * ze + (size_t)(n0 + wid * 32 + lr) * K + kb + lc;
    for (int s = 0; s < nst; ++s) {
      __syncthreads();
#pragma unroll
      for (int it = 0; it < 4; it++) {
        gload_lds16(Ag + (size_t)(it * 8) * K + s * 64, &As[(wid * 32 + it * 8) * 64]);
        gload_lds16(Bg + (size_t)(it * 8) * K + s * 64, &Bs[(wid * 32 + it * 8) * 64]);
      }
      __syncthreads();
#pragma unroll
      for (int kk = 0; kk < 2; kk++) {
        bf16x8 af[4], bfr[4];
        const int ko = kk * 32 + ksl * 8;
#pragma unroll
        for (int i = 0; i < 4; i++)
          af[i] = *(const bf16x8*)&As[(wm + i * 16 + l15) * 64 + ko];
#pragma unroll
        for (int j = 0; j < 4; j++)
          bfr[j] = *(const bf16x8*)&Bs[(wn + j * 16 + l15) * 64 + ko];
#pragma unroll
        for (int i = 0; i < 4; i++)
#pragma unroll
          for (int j = 0; j < 4; j++)
            acc[i][j] = mfma16(af[i], bfr[j], acc[i][j]);
      }
    }
  } else {
    // reg-staged 2-deep pipelined: thread covers (row = flat>>3, col = (flat&7)*8)
    const int sr = tid >> 3, sc = (tid & 7) * 8;
    const bf16* Ag = A + zA * ze + (size_t)(m0 + sr) * K + kb + sc;
    const bf16* Bg = Bw + zB * ze + (size_t)(n0 + sr) * K + kb + sc;
    bf16x8 avA[4], bvA[4], avB[4], bvB[4];
#pragma unroll
    for (int it = 0; it < 4; it++) {
      avA[it] = *(const bf16x8*)(Ag + (size_t)(it * 32) * K);
      bvA[it] = *(const bf16x8*)(Bg + (size_t)(it * 32) * K);
    }
#pragma unroll
    for (int it = 0; it < 4; it++) {
      avB[it] = *(const bf16x8*)(Ag + (size_t)(it * 32) * K + 64);
      bvB[it] = *(const bf16x8*)(Bg + (size_t)(it * 32) * K + 64);
    }
    auto compute = [&]() {
#pragma unroll
      for (int kk = 0; kk < 2; kk++) {
        bf16x8 af[4], bfr[4];
        const int ko = kk * 32 + ksl * 8;
#pragma unroll
        for (int i = 0; i < 4; i++)
          af[i] = *(const bf16x8*)&As[(wm + i * 16 + l15) * LDB + ko];
#pragma unroll
        for (int j = 0; j < 4; j++)
          bfr[j] = *(const bf16x8*)&Bs[(wn + j * 16 + l15) * LDB + ko];
#pragma unroll
        for (int i = 0; i < 4; i++)
#pragma unroll
          for (int j = 0; j < 4; j++)
            acc[i][j] = mfma16(af[i], bfr[j], acc[i][j]);
      }
    };
    for (int s = 0; s < nst; s += 2) {
      // even step: buffer A holds tile s
      __syncthreads();  // previous step's LDS reads done
#pragma unroll
      for (int it = 0; it < 4; it++) {
        *(bf16x8*)&As[(sr + it * 32) * LDB + sc] = avA[it];
        *(bf16x8*)&Bs[(sr + it * 32) * LDB + sc] = bvA[it];
      }
      __syncthreads();  // tile s visible
      if (s + 2 < nst) {  // issue loads for tile s+2; ~2 steps to land
#pragma unroll
        for (int it = 0; it < 4; it++) {
          avA[it] = *(const bf16x8*)(Ag + (size_t)(it * 32) * K + (s + 2) * 64);
          bvA[it] = *(const bf16x8*)(Bg + (size_t)(it * 32) * K + (s + 2) * 64);
        }
      }
      compute();
      // odd step: buffer B holds tile s+1
      __syncthreads();
#pragma unroll
      for (int it = 0; it < 4; it++) {
        *(bf16x8*)&As[(sr + it * 32) * LDB + sc] = avB[it];
        *(bf16x8*)&Bs[(sr + it * 32) * LDB + sc] = bvB[it];
      }
      __syncthreads();
      if (s + 3 < nst) {
#pragma unroll
        for (int it = 0; it < 4; it++) {
          avB[it] = *(const bf16x8*)(Ag + (size_t)(it * 32) * K + (s + 3) * 64);
          bvB[it] = *(const bf16x8*)(Bg + (size_t)(it * 32) * K + (s + 3) * 64);
        }
      }
      compute();
    }
  }

#pragma unroll
  for (int i = 0; i < 4; i++) {
#pragma unroll
    for (int j = 0; j < 4; j++) {
      const int mb = m0 + wm + i * 16 + ksl * 4;
      const int nc = n0 + wn + j * 16 + l15;
#pragma unroll
      for (int r = 0; r < 4; r++) {
        const int mr = mb + r;
        float vacc = acc[i][j][r];
        if constexpr (EPI == EPI_SPLIT_QKV) {
          const int h = nc / 192;
          const int rr = nc - h * 192;
          const int which = rr >> 6;
          const int d = rr & 63;
          const int b = mr >> 11, t = mr & 2047;
          bf16* dst = (which == 0) ? (bf16*)Out : (which == 1 ? k_out : v_out);
          dst[(((size_t)(b * NH + h)) * NT + t) * HD_ + d] = (bf16)vacc;
        } else if constexpr (EPI == EPI_ADD_X) {
          ((float*)Out)[(size_t)mr * N + nc] = vacc + Xadd[(size_t)mr * N + nc];
        } else if constexpr (EPI == EPI_BIAS_GELU) {
          // exact erf gelu -- PINNED. Measured optimum (VGPR 80, Occ 26%).
          // All cheap-gelu forms (div/rcp/raw-exp2) push VGPR to 92 and
          // cost an occupancy wave: r11/r13/r16 all regressed ~10 us.
          float x = vacc + bias[zBias * ze + nc];
          float gl = 0.5f * x * (1.f + erff(x * 0.70710678118654752f));
          ((bf16*)Out)[zOut * ze + (size_t)mr * N + nc] = (bf16)gl;
        } else {  // EPI_STORE: per-K-chunk bf16 partial (chunk stride = zOut*NE)
          ((bf16*)Out)[((size_t)kc * NE + ze) * zOut + (size_t)mr * N + nc] = (bf16)vacc;
        }
      }
    }
  }
}

// ---------------- rope apply (in-place on q,k); q also scaled by 0.125*log2(e) ----------------
__global__ __launch_bounds__(256) void rope_k(bf16* __restrict__ q, bf16* __restrict__ k,
                                              const float* __restrict__ tab) {
  const int bh = blockIdx.y;
  const int t = blockIdx.x * 4 + (threadIdx.x >> 6);
  const int d = threadIdx.x & 63;
  const size_t row = ((size_t)bh * NT + t) * HD_;
  const int i = d & 31;
  const float sn = tab[(t * 32 + i) * 2], cs = tab[(t * 32 + i) * 2 + 1];
  {
    float a = (float)q[row + d];
    float b2 = (float)q[row + (d ^ 32)];
    float o = (d < 32) ? (a * cs - b2 * sn) : (b2 * sn + a * cs);
    q[row + d] = (bf16)(o * 0.18033688011112042f);  // 0.125 * log2(e)
  }
  {
    float a = (float)k[row + d];
    float b2 = (float)k[row + (d ^ 32)];
    float o = (d < 32) ? (a * cs - b2 * sn) : (b2 * sn + a * cs);
    k[row + d] = (bf16)o;
  }
}

// ---------------- flash attention: swapped 32x32 MFMA, in-register softmax ----------------
// exp2 via raw v_exp_f32 builtin: r16's 2-factor experiment showed ~7 us win
// here (33 calls/tile; libm exp2f carries range-check overhead).
__global__ __launch_bounds__(256) void attn_k(const bf16* __restrict__ q,
                                              const bf16* __restrict__ k,
                                              const bf16* __restrict__ vT,
                                              bf16* __restrict__ attn_out) {
  __shared__ __align__(16) bf16 Kt[64 * 64];
  __shared__ __align__(16) bf16 Vt[64 * 64];
  const int bid = blockIdx.x;
  const int bh = bid & 31;
  const int ti = (bid >> 5) & 7;
  const int qt = (bid >> 8) ? (15 - ti) : ti;  // causal balance: CU pairs (t,15-t)
  const int q0 = qt * 128;
  const int tid = threadIdx.x, lane = tid & 63, wid = tid >> 6;
  const int l31 = lane & 31, hi = lane >> 5;
  const int q0w = q0 + wid * 32;
  const int qrow = q0w + l31;
  const size_t base = (size_t)bh * (NT * HD_);
  const size_t baseT = (size_t)bh * (HD_ * NT);

  bf16x8 qf[4];
#pragma unroll
  for (int ks = 0; ks < 4; ks++)
    qf[ks] = *(const bf16x8*)(q + base + (size_t)qrow * HD_ + ks * 16 + hi * 8);

  f32x16 ot0, ot1;
#pragma unroll
  for (int r = 0; r < 16; r++) { ot0[r] = 0.f; ot1[r] = 0.f; }
  float m2 = -1e30f, l = 0.f;

  const int ntiles = qt * 2 + 2;
  const int swz = (l31 & 7);
  const int strow = tid >> 3, stc = tid & 7;
  const int cw0 = ((stc ^ (strow & 7)) * 8);
  bf16x8 kr[2], vr[2];
#pragma unroll
  for (int rr = 0; rr < 2; rr++) {  // preload tile 0
    kr[rr] = *(const bf16x8*)(k + base + (size_t)(strow + rr * 32) * HD_ + stc * 8);
    vr[rr] = *(const bf16x8*)(vT + baseT + (size_t)(strow + rr * 32) * NT + stc * 8);
  }

  for (int t = 0; t < ntiles; t++) {
    const int kv0 = t * 64;
    __syncthreads();  // previous tile's LDS reads done
#pragma unroll
    for (int rr = 0; rr < 2; rr++) {
      *(bf16x8*)&Kt[(strow + rr * 32) * 64 + cw0] = kr[rr];
      *(bf16x8*)&Vt[(strow + rr * 32) * 64 + cw0] = vr[rr];
    }
    __syncthreads();  // tile visible
    if (t + 1 < ntiles) {  // issue next-tile loads; hide under compute
      const int kn = kv0 + 64;
#pragma unroll
      for (int rr = 0; rr < 2; rr++) {
        kr[rr] = *(const bf16x8*)(k + base + (size_t)(kn + strow + rr * 32) * HD_ + stc * 8);
        vr[rr] = *(const bf16x8*)(vT + baseT + (size_t)(strow + rr * 32) * NT + kn + stc * 8);
      }
    }
    if (kv0 > q0w + 31) continue;

    f32x16 s0, s1;
#pragma unroll
    for (int r = 0; r < 16; r++) { s0[r] = 0.f; s1[r] = 0.f; }
#pragma unroll
    for (int ks = 0; ks < 4; ks++) {
      const int cw = (((ks * 2 + hi) ^ swz) * 8);
      bf16x8 ka0 = *(const bf16x8*)&Kt[l31 * 64 + cw];
      bf16x8 ka1 = *(const bf16x8*)&Kt[(l31 + 32) * 64 + cw];
      s0 = mfma32(ka0, qf[ks], s0);
      s1 = mfma32(ka1, qf[ks], s1);
    }

    float p[32];
#pragma unroll
    for (int r = 0; r < 16; r++) { p[r] = s0[r]; p[16 + r] = s1[r]; }
    if (kv0 + 63 > q0w) {  // diagonal tile: causal mask
#pragma unroll
      for (int sub = 0; sub < 2; sub++)
#pragma unroll
        for (int r = 0; r < 16; r++) {
          int kvg = kv0 + sub * 32 + (r & 3) + 8 * (r >> 2) + 4 * hi;
          if (kvg > qrow) p[sub * 16 + r] = -1e30f;
        }
    }
    float tm = p[0];
#pragma unroll
    for (int r = 1; r < 32; r++) tm = fmaxf(tm, p[r]);
    tm = fmaxf(tm, __shfl_xor(tm, 32, 64));
    if (!__all(tm <= m2 + 8.f)) {  // defer-max
      float mn = fmaxf(m2, tm);
      float sf = __builtin_amdgcn_exp2f(m2 - mn);
      m2 = mn;
      l *= sf;
#pragma unroll
      for (int r = 0; r < 16; r++) { ot0[r] *= sf; ot1[r] *= sf; }
    }
    float ts = 0.f;
#pragma unroll
    for (int r = 0; r < 32; r++) { p[r] = __builtin_amdgcn_exp2f(p[r] - m2); ts += p[r]; }
    ts += __shfl_xor(ts, 32, 64);
    l += ts;

#pragma unroll
    for (int ks = 0; ks < 4; ks++) {
      const int i0 = (ks >> 1) * 16 + (ks & 1) * 8;
      unsigned Aw = pk2(p[i0 + 0], p[i0 + 1]);
      unsigned Bw = pk2(p[i0 + 2], p[i0 + 3]);
      unsigned Cw = pk2(p[i0 + 4], p[i0 + 5]);
      unsigned Dw = pk2(p[i0 + 6], p[i0 + 7]);
      unsigned xA = (unsigned)__shfl_xor((int)Aw, 32, 64);
      unsigned xB = (unsigned)__shfl_xor((int)Bw, 32, 64);
      unsigned xC = (unsigned)__shfl_xor((int)Cw, 32, 64);
      unsigned xD = (unsigned)__shfl_xor((int)Dw, 32, 64);
      union { unsigned u[4]; bf16x8 v; } pa;
      pa.u[0] = hi ? xC : Aw;
      pa.u[1] = hi ? xD : Bw;
      pa.u[2] = hi ? Cw : xA;
      pa.u[3] = hi ? Dw : xB;
      const int cw = (((ks * 2 + hi) ^ swz) * 8);
      bf16x8 va0 = *(const bf16x8*)&Vt[l31 * 64 + cw];
      bf16x8 va1 = *(const bf16x8*)&Vt[(l31 + 32) * 64 + cw];
      ot0 = mfma32(va0, pa.v, ot0);
      ot1 = mfma32(va1, pa.v, ot1);
    }
  }

  const int b = bh >> 4, h = bh & 15;
  const float inv = 1.f / l;
  const size_t orow = ((size_t)(b * NT + qrow)) * ND + h * 64;
#pragma unroll
  for (int g = 0; g < 4; g++) {
    bf16x4 w0, w1;
#pragma unroll
    for (int c = 0; c < 4; c++) {
      w0[c] = (bf16)(ot0[g * 4 + c] * inv);
      w1[c] = (bf16)(ot1[g * 4 + c] * inv);
    }
    *(bf16x4*)(attn_out + orow + g * 8 + 4 * hi) = w0;
    *(bf16x4*)(attn_out + orow + 32 + g * 8 + 4 * hi) = w1;
  }
}

// ---------------- capacity scan (single wave, token order, batched loads) ----------------
__global__ void scan_k(const int* __restrict__ idx, int* __restrict__ slot,
                       int* __restrict__ kept) {
  const int lane = threadIdx.x;
  int base[8];
#pragma unroll
  for (int e = 0; e < 8; e++) base[e] = 0;
  const unsigned long long lm = (lane == 63) ? ~0ull : ((1ull << (lane + 1)) - 1);
  for (int cb = 0; cb < 64; cb += 8) {
    int2 ev[8];  // batch 8 chunks' (e0,e1) -- loads issue together, latency amortized
#pragma unroll
    for (int u = 0; u < 8; u++)
      ev[u] = ((const int2*)idx)[(cb + u) * 64 + lane];
#pragma unroll
    for (int u = 0; u < 8; u++) {
      const int n = (cb + u) * 64 + lane;
      const int e0 = ev[u].x, e1 = ev[u].y;
      int s0 = 0, s1 = 0;
#pragma unroll
      for (int e = 0; e < 8; e++) {
        unsigned long long m0 = __ballot(e0 == e);
        unsigned long long m1 = __ballot(e1 == e);
        unsigned long long m = m0 | m1;
        int pref = __popcll(m & lm);
        if (e0 == e) s0 = base[e] + pref - 1;
        if (e1 == e) s1 = base[e] + pref - 1;
        base[e] += __popcll(m);
      }
      slot[n * 2] = s0; slot[n * 2 + 1] = s1;
      kept[n * 2] = (s0 < NCAP) ? 1 : 0;
      kept[n * 2 + 1] = (s1 < NCAP) ? 1 : 0;
    }
  }
}

// ---------------- scatter tokens into expert buffers ----------------
__global__ __launch_bounds__(64) void scatter_k(const float* __restrict__ moe_in,
                                                const int* __restrict__ idx,
                                                const int* __restrict__ slot,
                                                const int* __restrict__ kept,
                                                bf16* __restrict__ buf) {
  const int a = blockIdx.x;
  if (!kept[a]) return;
  const int n = a >> 1;
  const int e = idx[a], s = slot[a];
  const float* src = moe_in + (size_t)n * ND;
  bf16* dst = buf + ((size_t)e * NCAP + s) * ND;
  for (int c = threadIdx.x * 4; c < 1024; c += 256) {
    f32x4 v = *(const f32x4*)(src + c);
    bf16x4 o;
    o[0] = (bf16)v[0]; o[1] = (bf16)v[1]; o[2] = (bf16)v[2]; o[3] = (bf16)v[3];
    *(bf16x4*)(dst + c) = o;
  }
}

// ---------------- gather expert outputs (2 K-partials + b2, gate) + residual ----------------
__global__ __launch_bounds__(256) void gather_k(const float* __restrict__ h,
                                                const bf16* __restrict__ eout,
                                                const int* __restrict__ idx,
                                                const int* __restrict__ slot,
                                                const int* __restrict__ kept,
                                                const float* __restrict__ gv,
                                                const float* __restrict__ b2,
                                                float* __restrict__ out) {
  const size_t PS = (size_t)NE * NCAP * ND;  // partial stride
  const int n = blockIdx.x;
  const int k0 = kept[n * 2], k1 = kept[n * 2 + 1];
  const int i0 = idx[n * 2], i1 = idx[n * 2 + 1];
  const float g0 = k0 ? gv[n * 2] : 0.f;
  const float g1 = k1 ? gv[n * 2 + 1] : 0.f;
  const size_t r0 = k0 ? ((size_t)i0 * NCAP + slot[n * 2]) * ND : 0;
  const size_t r1 = k1 ? ((size_t)i1 * NCAP + slot[n * 2 + 1]) * ND : 0;
  const int c = threadIdx.x * 4;
  f32x4 o = *(const f32x4*)(h + (size_t)n * ND + c);
  if (k0) {
    bf16x4 ea = *(const bf16x4*)(eout + r0 + c);
    bf16x4 eb = *(const bf16x4*)(eout + PS + r0 + c);
    f32x4 bb = *(const f32x4*)(b2 + i0 * ND + c);
#pragma unroll
    for (int cc = 0; cc < 4; cc++)
      o[cc] += g0 * ((float)ea[cc] + (float)eb[cc] + bb[cc]);
  }
  if (k1) {
    bf16x4 ea = *(const bf16x4*)(eout + r1 + c);
    bf16x4 eb = *(const bf16x4*)(eout + PS + r1 + c);
    f32x4 bb = *(const f32x4*)(b2 + i1 * ND + c);
#pragma unroll
    for (int cc = 0; cc < 4; cc++)
      o[cc] += g1 * ((float)ea[cc] + (float)eb[cc] + bb[cc]);
  }
  *(f32x4*)(out + (size_t)n * ND + c) = o;
}

// ---------------- launcher ----------------
extern "C" void kernel_launch(void* const* d_in, const int* in_sizes, int n_in,
                              void* d_out, int out_size, void* d_ws, size_t ws_size,
                              hipStream_t stream) {
  (void)in_sizes; (void)n_in; (void)out_size;
  const float* x      = (const float*)d_in[0];
  const float* ln1_g  = (const float*)d_in[1];
  const float* ln1_b  = (const float*)d_in[2];
  const float* w_qkv  = (const float*)d_in[3];
  const float* w_proj = (const float*)d_in[4];
  const float* ln2_g  = (const float*)d_in[5];
  const float* ln2_b  = (const float*)d_in[6];
  const float* w_gate = (const float*)d_in[7];
  const float* w1     = (const float*)d_in[8];
  const float* b1     = (const float*)d_in[9];
  const float* w2     = (const float*)d_in[10];
  const float* b2     = (const float*)d_in[11];
  float* out = (float*)d_out;

  char* ws = (char*)d_ws;
  size_t off = 0;
  auto alloc = [&](size_t bytes) -> char* {
    char* p = ws + off;
    off += (bytes + 255) & ~(size_t)255;
    return p;
  };
  bf16* w1t    = (bf16*)alloc((size_t)NE * NDFF * ND * 2);     // 67.1 MB
  bf16* w2t    = (bf16*)alloc((size_t)NE * ND * NDFF * 2);     // 67.1 MB
  bf16* wqkvb  = (bf16*)alloc((size_t)3 * ND * ND * 2);        // 6.29 MB
  bf16* wprojb = (bf16*)alloc((size_t)ND * ND * 2);            // 2.10 MB
  float* hbufr = (float*)alloc((size_t)NTOK * ND * 4);         // h, 16.78 MB
  float* moein = (float*)alloc((size_t)NTOK * ND * 4);         // 16.78 MB
  float* ropet = (float*)alloc((size_t)NT * 32 * 2 * 4);       // 0.52 MB
  int*   idx   = (int*)alloc((size_t)NTOK * 2 * 4);
  int*   slot  = (int*)alloc((size_t)NTOK * 2 * 4);
  int*   kept  = (int*)alloc((size_t)NTOK * 2 * 4);
  float* gv    = (float*)alloc((size_t)NTOK * 2 * 4);
  char*  S     = alloc((size_t)62914560);                      // 62.9 MB shared region
  if (off > ws_size) return;

  // phase A layout (attention)
  const size_t MB8 = (size_t)8388608;
  bf16* xn    = (bf16*)(S);
  bf16* qp    = (bf16*)(S + MB8);
  bf16* kp    = (bf16*)(S + 2 * MB8);
  bf16* vp    = (bf16*)(S + 3 * MB8);
  bf16* attnp = (bf16*)(S + 4 * MB8);
  bf16* vTp   = (bf16*)(S);                       // alias xn (dead after qkv gemm)
  // phase B layout (MoE): hbuf [0,41.9M), buf [41.9,52.4M),
  // eout (2 bf16 partials, 21 MB) [41.9,62.9M) -- aliases buf after gemm1.
  bf16* hbuf  = (bf16*)(S);
  bf16* buf   = (bf16*)(S + (size_t)41943040);
  bf16* eout  = (bf16*)(S + (size_t)41943040);

  dim3 tb(32, 8);
  cvt_k<<<2048, 256, 0, stream>>>(w_qkv, wqkvb, 3 * ND * ND / 4);
  cvt_k<<<1024, 256, 0, stream>>>(w_proj, wprojb, ND * ND / 4);
  transpose_k<<<dim3(NDFF / 64, ND / 64, NE), 256, 0, stream>>>(w1, w1t, ND, NDFF);
  transpose_k<<<dim3(ND / 64, NDFF / 64, NE), 256, 0, stream>>>(w2, w2t, NDFF, ND);
  rope_tab_k<<<NT, 32, 0, stream>>>(ropet);
  ln_k<<<NTOK, 256, 0, stream>>>(x, ln1_g, ln1_b, xn);
  // qkv: grid 768 (3 blocks/CU) -> gload 1-phase
  gemm_bt_k<EPI_SPLIT_QKV, 0, false, 1, false>
      <<<dim3(3 * ND / 128, NTOK / 128, 1), 256, 0, stream>>>(
      xn, wqkvb, NTOK, 3 * ND, ND, 0, 0, 0, 0, nullptr, nullptr, qp, kp, vp);
  transpose_v_k<<<dim3(NT / 32, HD_ / 32, NB * NH), tb, 0, stream>>>(vp, vTp);
  rope_k<<<dim3(NT / 4, NB * NH), 256, 0, stream>>>(qp, kp, ropet);
  attn_k<<<512, 256, 0, stream>>>(qp, kp, vTp, attnp);
  // proj: grid 256 (1 block/CU) -> reg-staged 2-deep pipelined, padded LDS
  gemm_bt_k<EPI_ADD_X, 1, true, 1, false>
      <<<dim3(ND / 128, NTOK / 128, 1), 256, 0, stream>>>(
      attnp, wprojb, NTOK, ND, ND, 0, 0, 0, 0, nullptr, x, hbufr, nullptr, nullptr);
  // fused ln2 + gating
  ln_gate_k<<<NTOK, 256, 0, stream>>>(hbufr, ln2_g, ln2_b, w_gate, moein, idx, gv);
  scan_k<<<1, 64, 0, stream>>>(idx, slot, kept);
  scatter_k<<<NTOK * 2, 64, 0, stream>>>(moein, idx, slot, kept, buf);
  // moe GEMM1: grid 1280 (5 blocks/CU) -> gload 1-phase, erff gelu, XCD swizzle
  gemm_bt_k<EPI_BIAS_GELU, 0, false, 1, true>
      <<<dim3(NDFF / 128, NCAP / 128, NE), 256, 0, stream>>>(
      buf, w1t, NCAP, NDFF, ND, (size_t)NCAP * ND, (size_t)NDFF * ND,
      (size_t)NCAP * NDFF, NDFF, b1, nullptr, hbuf, nullptr, nullptr);
  // moe GEMM2: split-K=2 (grid 640), reg-staged 2-deep, bf16 partials, XCD swizzle
  gemm_bt_k<EPI_STORE, 1, true, 2, true>
      <<<dim3(ND / 128, NCAP / 128, NE * 2), 256, 0, stream>>>(
      hbuf, w2t, NCAP, ND, NDFF, (size_t)NCAP * NDFF, (size_t)ND * NDFF,
      (size_t)NCAP * ND, 0, nullptr, nullptr, eout, nullptr, nullptr);
  gather_k<<<NTOK, 256, 0, stream>>>(hbufr, eout, idx, slot, kept, gv, b2, out);
}

// Round 18
// 420.514 us; speedup vs baseline: 1.0351x; 1.0128x over previous
//
#include <hip/hip_runtime.h>
#include <hip/hip_bf16.h>

typedef __bf16 bf16;
typedef __attribute__((ext_vector_type(8))) __bf16 bf16x8;
typedef __attribute__((ext_vector_type(4))) __bf16 bf16x4;
typedef __attribute__((ext_vector_type(4))) float f32x4;
typedef __attribute__((ext_vector_type(16))) float f32x16;

#define NB 2
#define NT 2048
#define ND 1024
#define NH 16
#define HD_ 64
#define NE 8
#define NCAP 640
#define NTOK 4096
#define NDFF 4096

static __device__ __forceinline__ f32x4 mfma16(bf16x8 a, bf16x8 b, f32x4 c) {
  return __builtin_amdgcn_mfma_f32_16x16x32_bf16(a, b, c, 0, 0, 0);
}
static __device__ __forceinline__ f32x16 mfma32(bf16x8 a, bf16x8 b, f32x16 c) {
  return __builtin_amdgcn_mfma_f32_32x32x16_bf16(a, b, c, 0, 0, 0);
}
static __device__ __forceinline__ unsigned pk2(float a, float b) {
  union { __bf16 h[2]; unsigned u; } z;
  z.h[0] = (__bf16)a; z.h[1] = (__bf16)b;
  return z.u;
}
static __device__ __forceinline__ void gload_lds16(const bf16* g, bf16* l) {
  __builtin_amdgcn_global_load_lds(
      (const __attribute__((address_space(1))) unsigned int*)g,
      (__attribute__((address_space(3))) unsigned int*)l, 16, 0, 0);
}

// ---------------- elementwise f32 -> bf16 convert ----------------
__global__ __launch_bounds__(256) void cvt_k(const float* __restrict__ in,
                                             bf16* __restrict__ out, int n4) {
  int i = blockIdx.x * 256 + threadIdx.x;
  int stride = gridDim.x * 256;
  for (; i < n4; i += stride) {
    f32x4 v = ((const f32x4*)in)[i];
    bf16x4 o;
    o[0] = (bf16)v[0]; o[1] = (bf16)v[1]; o[2] = (bf16)v[2]; o[3] = (bf16)v[3];
    ((bf16x4*)out)[i] = o;
  }
}

// ---------------- transpose f32 (R,C) -> bf16 (C,R), 64x64 tiles, batched z ----------------
__global__ __launch_bounds__(256) void transpose_k(const float* __restrict__ in,
                                                   bf16* __restrict__ out, int R, int C) {
  __shared__ float tile[64][65];
  const size_t zoff = (size_t)blockIdx.z * R * C;
  in += zoff; out += zoff;
  const int c0 = blockIdx.x * 64, r0 = blockIdx.y * 64;
  const int tx = threadIdx.x & 15, ty = threadIdx.x >> 4;  // 16 x 16
#pragma unroll
  for (int i = 0; i < 4; i++) {
    const int r = i * 16 + ty;
    f32x4 v = *(const f32x4*)(in + (size_t)(r0 + r) * C + c0 + tx * 4);
    *(f32x4*)&tile[r][tx * 4] = v;
  }
  __syncthreads();
#pragma unroll
  for (int i = 0; i < 4; i++) {
    const int rr = i * 16 + ty;  // output row within tile (= source col)
    bf16x4 o;
#pragma unroll
    for (int j = 0; j < 4; j++) o[j] = (bf16)tile[tx * 4 + j][rr];
    *(bf16x4*)(out + (size_t)(c0 + rr) * R + r0 + tx * 4) = o;
  }
}

// ---------------- transpose bf16 v (per bh: (T,HD) -> (HD,T)) ----------------
__global__ __launch_bounds__(256) void transpose_v_k(const bf16* __restrict__ v,
                                                     bf16* __restrict__ vT) {
  __shared__ bf16 tile[32][33];
  int bh = blockIdx.z;
  const bf16* in = v + (size_t)bh * NT * HD_;
  bf16* out = vT + (size_t)bh * HD_ * NT;
  int t0 = blockIdx.x * 32, d0 = blockIdx.y * 32;
  int tx = threadIdx.x, ty = threadIdx.y;
#pragma unroll
  for (int i = 0; i < 4; i++)
    tile[ty + i * 8][tx] = in[(size_t)(t0 + ty + i * 8) * HD_ + d0 + tx];
  __syncthreads();
#pragma unroll
  for (int i = 0; i < 4; i++)
    out[(size_t)(d0 + ty + i * 8) * NT + t0 + tx] = tile[tx][ty + i * 8];
}

// ---------------- rope sin/cos table ----------------
__global__ void rope_tab_k(float* __restrict__ tab) {
  int t = blockIdx.x, i = threadIdx.x;  // 32 threads
  float inv = powf(10000.f, -(float)(2 * i) * (1.f / 64.f));
  float ang = (float)t * inv;
  float s, c;
  sincosf(ang, &s, &c);
  tab[(t * 32 + i) * 2] = s;
  tab[(t * 32 + i) * 2 + 1] = c;
}

// ---------------- layernorm (row of 1024) -> bf16 ----------------
__global__ __launch_bounds__(256) void ln_k(const float* __restrict__ in,
                                            const float* __restrict__ g,
                                            const float* __restrict__ bb,
                                            bf16* __restrict__ outb) {
  const int row = blockIdx.x;
  const float* xr = in + (size_t)row * ND;
  const int tid = threadIdx.x, lane = tid & 63, wid = tid >> 6;
  f32x4 v = ((const f32x4*)xr)[tid];
  float s = v[0] + v[1] + v[2] + v[3];
  float sq = v[0] * v[0] + v[1] * v[1] + v[2] * v[2] + v[3] * v[3];
#pragma unroll
  for (int m = 1; m < 64; m <<= 1) {
    s += __shfl_xor(s, m, 64);
    sq += __shfl_xor(sq, m, 64);
  }
  __shared__ float red[8];
  if (lane == 0) { red[wid] = s; red[4 + wid] = sq; }
  __syncthreads();
  s = red[0] + red[1] + red[2] + red[3];
  sq = red[4] + red[5] + red[6] + red[7];
  float mean = s * (1.f / 1024.f);
  float var = sq * (1.f / 1024.f) - mean * mean;
  float rs = rsqrtf(var + 1e-5f);
#pragma unroll
  for (int c = 0; c < 4; c++) {
    int col = tid * 4 + c;
    float y = (v[c] - mean) * rs * g[col] + bb[col];
    outb[(size_t)row * ND + col] = (bf16)y;
  }
}

// ---------------- fused layernorm + gate (logits, softmax, top2) ----------------
__global__ __launch_bounds__(256) void ln_gate_k(const float* __restrict__ in,
                                                 const float* __restrict__ g,
                                                 const float* __restrict__ bb,
                                                 const float* __restrict__ w_gate,
                                                 float* __restrict__ moein,
                                                 int* __restrict__ idx,
                                                 float* __restrict__ gv) {
  const int row = blockIdx.x;
  const float* xr = in + (size_t)row * ND;
  const int tid = threadIdx.x, lane = tid & 63, wid = tid >> 6;
  f32x4 v = ((const f32x4*)xr)[tid];
  float s = v[0] + v[1] + v[2] + v[3];
  float sq = v[0] * v[0] + v[1] * v[1] + v[2] * v[2] + v[3] * v[3];
#pragma unroll
  for (int m = 1; m < 64; m <<= 1) {
    s += __shfl_xor(s, m, 64);
    sq += __shfl_xor(sq, m, 64);
  }
  __shared__ float red[8];
  if (lane == 0) { red[wid] = s; red[4 + wid] = sq; }
  __syncthreads();
  s = red[0] + red[1] + red[2] + red[3];
  sq = red[4] + red[5] + red[6] + red[7];
  float mean = s * (1.f / 1024.f);
  float var = sq * (1.f / 1024.f) - mean * mean;
  float rs = rsqrtf(var + 1e-5f);
  f32x4 y;
#pragma unroll
  for (int c = 0; c < 4; c++) {
    int col = tid * 4 + c;
    y[c] = (v[c] - mean) * rs * g[col] + bb[col];
  }
  *(f32x4*)(moein + (size_t)row * ND + tid * 4) = y;
  // gate logits: 8 dot products of the normalized row with w_gate rows
  float a[8];
#pragma unroll
  for (int e = 0; e < 8; e++) {
    f32x4 wv = *(const f32x4*)(w_gate + e * ND + tid * 4);
    a[e] = y[0] * wv[0] + y[1] * wv[1] + y[2] * wv[2] + y[3] * wv[3];
  }
#pragma unroll
  for (int e = 0; e < 8; e++)
#pragma unroll
    for (int m = 1; m < 64; m <<= 1) a[e] += __shfl_xor(a[e], m, 64);
  __shared__ float red2[4][8];
  if (lane < 8) red2[wid][lane] = a[lane];
  __syncthreads();
  if (tid == 0) {
    float t[8];
#pragma unroll
    for (int e = 0; e < 8; e++)
      t[e] = red2[0][e] + red2[1][e] + red2[2][e] + red2[3][e];
    float mx = t[0];
#pragma unroll
    for (int e = 1; e < 8; e++) mx = fmaxf(mx, t[e]);
    float p[8], se = 0.f;
#pragma unroll
    for (int e = 0; e < 8; e++) { p[e] = expf(t[e] - mx); se += p[e]; }
    float inv = 1.f / se;
#pragma unroll
    for (int e = 0; e < 8; e++) p[e] *= inv;
    int i1 = 0; float v1 = p[0];
#pragma unroll
    for (int e = 1; e < 8; e++) if (p[e] > v1) { v1 = p[e]; i1 = e; }
    int i2 = -1; float v2 = -1.f;
#pragma unroll
    for (int e = 0; e < 8; e++) if (e != i1 && p[e] > v2) { v2 = p[e]; i2 = e; }
    idx[row * 2] = i1; idx[row * 2 + 1] = i2;
    gv[row * 2] = v1; gv[row * 2 + 1] = v2;
  }
}

// ---------------- GEMM: C(M,N) = A(M,K) * B(N,K)^T, bf16 in, f32 accum ----------------
// STAGE=0: m97 gload_lds 1-phase (linear LDS), right at >=3 blocks/CU.
// STAGE=1: reg-staged 2-DEEP pipelined (named buffers, step-unrolled x2 --
//   rule #20), right at low blocks/CU. Requires nst even (proj 16, GEMM2 32).
// NSPLIT (compile-time): split-K; EPI_STORE writes per-chunk bf16 partials.
// MSWZ: XCD-locality swizzle -- m-tiles sharing one B-panel land on one XCD.
#define EPI_SPLIT_QKV 0
#define EPI_ADD_X 1
#define EPI_BIAS_GELU 2
#define EPI_STORE 3

template <int EPI, int STAGE, bool PAD, int NSPLIT, bool MSWZ>
__global__ __launch_bounds__(256) void gemm_bt_k(
    const bf16* __restrict__ A, const bf16* __restrict__ Bw,
    const int M, const int N, const int K,
    const size_t zA, const size_t zB, const size_t zOut, const size_t zBias,
    const float* __restrict__ bias, const float* __restrict__ Xadd,
    void* __restrict__ Out, bf16* __restrict__ k_out, bf16* __restrict__ v_out) {
  int bx = blockIdx.x, by = blockIdx.y, bz = blockIdx.z;
  if constexpr (MSWZ) {
    const int gx = gridDim.x, gy = gridDim.y;
    int lin = bx + gx * (by + gy * bz);
    int xcd = lin & 7;
    int t = lin >> 3;
    by = t % gy;              // m-tile
    int gq = t / gy;
    int gg = gq * 8 + xcd;    // (n, z) panel id
    bx = gg % gx;
    bz = gg / gx;
  }
  const int z = bz;
  const int ze = z / NSPLIT;
  const int kc = z % NSPLIT;
  const int klen = K / NSPLIT;
  const int kb = kc * klen;
  const int nst = klen / 64;
  const int m0 = by * 128, n0 = bx * 128;
  const int tid = threadIdx.x, lane = tid & 63, wid = tid >> 6;
  const int wm = (wid >> 1) * 64, wn = (wid & 1) * 64;
  const int l15 = lane & 15, ksl = lane >> 4;
  constexpr int LDB = (STAGE == 1 && PAD) ? 72 : 64;
  __shared__ __align__(16) bf16 As[128 * LDB];
  __shared__ __align__(16) bf16 Bs[128 * LDB];
  f32x4 acc[4][4];
#pragma unroll
  for (int i = 0; i < 4; i++)
#pragma unroll
    for (int j = 0; j < 4; j++) acc[i][j] = (f32x4){0.f, 0.f, 0.f, 0.f};

  if constexpr (STAGE == 0) {
    const int lr = lane >> 3, lc = (lane & 7) * 8;
    const bf16* Ag = A + zA * ze + (size_t)(m0 + wid * 32 + lr) * K + kb + lc;
    const bf16* Bg = Bw + zB * ze + (size_t)(n0 + wid * 32 + lr) * K + kb + lc;
    for (int s = 0; s < nst; ++s) {
      __syncthreads();
#pragma unroll
      for (int it = 0; it < 4; it++) {
        gload_lds16(Ag + (size_t)(it * 8) * K + s * 64, &As[(wid * 32 + it * 8) * 64]);
        gload_lds16(Bg + (size_t)(it * 8) * K + s * 64, &Bs[(wid * 32 + it * 8) * 64]);
      }
      __syncthreads();
#pragma unroll
      for (int kk = 0; kk < 2; kk++) {
        bf16x8 af[4], bfr[4];
        const int ko = kk * 32 + ksl * 8;
#pragma unroll
        for (int i = 0; i < 4; i++)
          af[i] = *(const bf16x8*)&As[(wm + i * 16 + l15) * 64 + ko];
#pragma unroll
        for (int j = 0; j < 4; j++)
          bfr[j] = *(const bf16x8*)&Bs[(wn + j * 16 + l15) * 64 + ko];
#pragma unroll
        for (int i = 0; i < 4; i++)
#pragma unroll
          for (int j = 0; j < 4; j++)
            acc[i][j] = mfma16(af[i], bfr[j], acc[i][j]);
      }
    }
  } else {
    // reg-staged 2-deep pipelined: thread covers (row = flat>>3, col = (flat&7)*8)
    const int sr = tid >> 3, sc = (tid & 7) * 8;
    const bf16* Ag = A + zA * ze + (size_t)(m0 + sr) * K + kb + sc;
    const bf16* Bg = Bw + zB * ze + (size_t)(n0 + sr) * K + kb + sc;
    bf16x8 avA[4], bvA[4], avB[4], bvB[4];
#pragma unroll
    for (int it = 0; it < 4; it++) {
      avA[it] = *(const bf16x8*)(Ag + (size_t)(it * 32) * K);
      bvA[it] = *(const bf16x8*)(Bg + (size_t)(it * 32) * K);
    }
#pragma unroll
    for (int it = 0; it < 4; it++) {
      avB[it] = *(const bf16x8*)(Ag + (size_t)(it * 32) * K + 64);
      bvB[it] = *(const bf16x8*)(Bg + (size_t)(it * 32) * K + 64);
    }
    auto compute = [&]() {
#pragma unroll
      for (int kk = 0; kk < 2; kk++) {
        bf16x8 af[4], bfr[4];
        const int ko = kk * 32 + ksl * 8;
#pragma unroll
        for (int i = 0; i < 4; i++)
          af[i] = *(const bf16x8*)&As[(wm + i * 16 + l15) * LDB + ko];
#pragma unroll
        for (int j = 0; j < 4; j++)
          bfr[j] = *(const bf16x8*)&Bs[(wn + j * 16 + l15) * LDB + ko];
#pragma unroll
        for (int i = 0; i < 4; i++)
#pragma unroll
          for (int j = 0; j < 4; j++)
            acc[i][j] = mfma16(af[i], bfr[j], acc[i][j]);
      }
    };
    for (int s = 0; s < nst; s += 2) {
      // even step: buffer A holds tile s
      __syncthreads();  // previous step's LDS reads done
#pragma unroll
      for (int it = 0; it < 4; it++) {
        *(bf16x8*)&As[(sr + it * 32) * LDB + sc] = avA[it];
        *(bf16x8*)&Bs[(sr + it * 32) * LDB + sc] = bvA[it];
      }
      __syncthreads();  // tile s visible
      if (s + 2 < nst) {  // issue loads for tile s+2; ~2 steps to land
#pragma unroll
        for (int it = 0; it < 4; it++) {
          avA[it] = *(const bf16x8*)(Ag + (size_t)(it * 32) * K + (s + 2) * 64);
          bvA[it] = *(const bf16x8*)(Bg + (size_t)(it * 32) * K + (s + 2) * 64);
        }
      }
      compute();
      // odd step: buffer B holds tile s+1
      __syncthreads();
#pragma unroll
      for (int it = 0; it < 4; it++) {
        *(bf16x8*)&As[(sr + it * 32) * LDB + sc] = avB[it];
        *(bf16x8*)&Bs[(sr + it * 32) * LDB + sc] = bvB[it];
      }
      __syncthreads();
      if (s + 3 < nst) {
#pragma unroll
        for (int it = 0; it < 4; it++) {
          avB[it] = *(const bf16x8*)(Ag + (size_t)(it * 32) * K + (s + 3) * 64);
          bvB[it] = *(const bf16x8*)(Bg + (size_t)(it * 32) * K + (s + 3) * 64);
        }
      }
      compute();
    }
  }

#pragma unroll
  for (int i = 0; i < 4; i++) {
#pragma unroll
    for (int j = 0; j < 4; j++) {
      const int mb = m0 + wm + i * 16 + ksl * 4;
      const int nc = n0 + wn + j * 16 + l15;
#pragma unroll
      for (int r = 0; r < 4; r++) {
        const int mr = mb + r;
        float vacc = acc[i][j][r];
        if constexpr (EPI == EPI_SPLIT_QKV) {
          const int h = nc / 192;
          const int rr = nc - h * 192;
          const int which = rr >> 6;
          const int d = rr & 63;
          const int b = mr >> 11, t = mr & 2047;
          bf16* dst = (which == 0) ? (bf16*)Out : (which == 1 ? k_out : v_out);
          dst[(((size_t)(b * NH + h)) * NT + t) * HD_ + d] = (bf16)vacc;
        } else if constexpr (EPI == EPI_ADD_X) {
          ((float*)Out)[(size_t)mr * N + nc] = vacc + Xadd[(size_t)mr * N + nc];
        } else if constexpr (EPI == EPI_BIAS_GELU) {
          // exact erf gelu -- PINNED. Measured optimum (VGPR 80, Occ 26%).
          // All cheap-gelu forms (div/rcp/raw-exp2) push VGPR to 92 and
          // cost an occupancy wave: r11/r13/r16 all regressed ~10 us.
          float x = vacc + bias[zBias * ze + nc];
          float gl = 0.5f * x * (1.f + erff(x * 0.70710678118654752f));
          ((bf16*)Out)[zOut * ze + (size_t)mr * N + nc] = (bf16)gl;
        } else {  // EPI_STORE: per-K-chunk bf16 partial (chunk stride = zOut*NE)
          ((bf16*)Out)[((size_t)kc * NE + ze) * zOut + (size_t)mr * N + nc] = (bf16)vacc;
        }
      }
    }
  }
}

// ---------------- rope apply (in-place on q,k); q also scaled by 0.125*log2(e) ----------------
__global__ __launch_bounds__(256) void rope_k(bf16* __restrict__ q, bf16* __restrict__ k,
                                              const float* __restrict__ tab) {
  const int bh = blockIdx.y;
  const int t = blockIdx.x * 4 + (threadIdx.x >> 6);
  const int d = threadIdx.x & 63;
  const size_t row = ((size_t)bh * NT + t) * HD_;
  const int i = d & 31;
  const float sn = tab[(t * 32 + i) * 2], cs = tab[(t * 32 + i) * 2 + 1];
  {
    float a = (float)q[row + d];
    float b2 = (float)q[row + (d ^ 32)];
    float o = (d < 32) ? (a * cs - b2 * sn) : (b2 * sn + a * cs);
    q[row + d] = (bf16)(o * 0.18033688011112042f);  // 0.125 * log2(e)
  }
  {
    float a = (float)k[row + d];
    float b2 = (float)k[row + (d ^ 32)];
    float o = (d < 32) ? (a * cs - b2 * sn) : (b2 * sn + a * cs);
    k[row + d] = (bf16)o;
  }
}

// ---------------- flash attention: swapped 32x32 MFMA, in-register softmax ----------------
// KVBLK=128: stage 128 KV rows per barrier pair (Kt[128][64], Vt[64][128],
// 32 KB LDS), compute the two 64-row subtiles sequentially -- halves barrier
// rounds (qt+1 vs 2qt+2). exp2 via raw v_exp_f32 builtin (r16: ~7 us win).
__global__ __launch_bounds__(256) void attn_k(const bf16* __restrict__ q,
                                              const bf16* __restrict__ k,
                                              const bf16* __restrict__ vT,
                                              bf16* __restrict__ attn_out) {
  __shared__ __align__(16) bf16 Kt[128 * 64];
  __shared__ __align__(16) bf16 Vt[64 * 128];
  const int bid = blockIdx.x;
  const int bh = bid & 31;
  const int ti = (bid >> 5) & 7;
  const int qt = (bid >> 8) ? (15 - ti) : ti;  // causal balance: CU pairs (t,15-t)
  const int q0 = qt * 128;
  const int tid = threadIdx.x, lane = tid & 63, wid = tid >> 6;
  const int l31 = lane & 31, hi = lane >> 5;
  const int q0w = q0 + wid * 32;
  const int qrow = q0w + l31;
  const size_t base = (size_t)bh * (NT * HD_);
  const size_t baseT = (size_t)bh * (HD_ * NT);

  bf16x8 qf[4];
#pragma unroll
  for (int ks = 0; ks < 4; ks++)
    qf[ks] = *(const bf16x8*)(q + base + (size_t)qrow * HD_ + ks * 16 + hi * 8);

  f32x16 ot0, ot1;
#pragma unroll
  for (int r = 0; r < 16; r++) { ot0[r] = 0.f; ot1[r] = 0.f; }
  float m2 = -1e30f, l = 0.f;

  const int nrounds = qt + 1;  // 128 KV rows per round
  const int swz = (l31 & 7);
  // staging: thread covers K rows strow+{0,32,64,96} col stc*8;
  //          V d-rows strow+{0,32} x kv-col-halves {0,64} at stc*8
  const int strow = tid >> 3, stc = tid & 7;
  const int cw0 = ((stc ^ (strow & 7)) * 8);  // swizzle const across +32/+64 rows
  bf16x8 kr[4], vr[4];
#pragma unroll
  for (int rr = 0; rr < 4; rr++)  // preload round 0: K rows 0..127
    kr[rr] = *(const bf16x8*)(k + base + (size_t)(strow + rr * 32) * HD_ + stc * 8);
#pragma unroll
  for (int rr = 0; rr < 2; rr++)
#pragma unroll
    for (int h2 = 0; h2 < 2; h2++)  // V: d rows 0..63, kv cols 0..127
      vr[rr * 2 + h2] = *(const bf16x8*)(vT + baseT + (size_t)(strow + rr * 32) * NT +
                                         h2 * 64 + stc * 8);

  for (int ro = 0; ro < nrounds; ro++) {
    const int kv0r = ro * 128;
    __syncthreads();  // previous round's LDS reads done
#pragma unroll
    for (int rr = 0; rr < 4; rr++)
      *(bf16x8*)&Kt[(strow + rr * 32) * 64 + cw0] = kr[rr];
#pragma unroll
    for (int rr = 0; rr < 2; rr++)
#pragma unroll
      for (int h2 = 0; h2 < 2; h2++)
        *(bf16x8*)&Vt[(strow + rr * 32) * 128 + h2 * 64 + cw0] = vr[rr * 2 + h2];
    __syncthreads();  // round visible
    if (ro + 1 < nrounds) {  // issue next-round loads; hide under compute
      const int kn = kv0r + 128;
#pragma unroll
      for (int rr = 0; rr < 4; rr++)
        kr[rr] = *(const bf16x8*)(k + base + (size_t)(kn + strow + rr * 32) * HD_ + stc * 8);
#pragma unroll
      for (int rr = 0; rr < 2; rr++)
#pragma unroll
        for (int h2 = 0; h2 < 2; h2++)
          vr[rr * 2 + h2] = *(const bf16x8*)(vT + baseT + (size_t)(strow + rr * 32) * NT +
                                             kn + h2 * 64 + stc * 8);
    }

#pragma unroll
    for (int sub = 0; sub < 2; sub++) {
      const int kv0 = kv0r + sub * 64;
      if (kv0 > q0w + 31) break;  // later subs only larger -- done this round

      f32x16 s0, s1;
#pragma unroll
      for (int r = 0; r < 16; r++) { s0[r] = 0.f; s1[r] = 0.f; }
#pragma unroll
      for (int ks = 0; ks < 4; ks++) {
        const int cw = (((ks * 2 + hi) ^ swz) * 8);
        bf16x8 ka0 = *(const bf16x8*)&Kt[(sub * 64 + l31) * 64 + cw];
        bf16x8 ka1 = *(const bf16x8*)&Kt[(sub * 64 + l31 + 32) * 64 + cw];
        s0 = mfma32(ka0, qf[ks], s0);
        s1 = mfma32(ka1, qf[ks], s1);
      }

      float p[32];
#pragma unroll
      for (int r = 0; r < 16; r++) { p[r] = s0[r]; p[16 + r] = s1[r]; }
      if (kv0 + 63 > q0w) {  // diagonal tile: causal mask
#pragma unroll
        for (int s2 = 0; s2 < 2; s2++)
#pragma unroll
          for (int r = 0; r < 16; r++) {
            int kvg = kv0 + s2 * 32 + (r & 3) + 8 * (r >> 2) + 4 * hi;
            if (kvg > qrow) p[s2 * 16 + r] = -1e30f;
          }
      }
      float tm = p[0];
#pragma unroll
      for (int r = 1; r < 32; r++) tm = fmaxf(tm, p[r]);
      tm = fmaxf(tm, __shfl_xor(tm, 32, 64));
      if (!__all(tm <= m2 + 8.f)) {  // defer-max
        float mn = fmaxf(m2, tm);
        float sf = __builtin_amdgcn_exp2f(m2 - mn);
        m2 = mn;
        l *= sf;
#pragma unroll
        for (int r = 0; r < 16; r++) { ot0[r] *= sf; ot1[r] *= sf; }
      }
      float ts = 0.f;
#pragma unroll
      for (int r = 0; r < 32; r++) { p[r] = __builtin_amdgcn_exp2f(p[r] - m2); ts += p[r]; }
      ts += __shfl_xor(ts, 32, 64);
      l += ts;

#pragma unroll
      for (int ks = 0; ks < 4; ks++) {
        const int i0 = (ks >> 1) * 16 + (ks & 1) * 8;
        unsigned Aw = pk2(p[i0 + 0], p[i0 + 1]);
        unsigned Bw = pk2(p[i0 + 2], p[i0 + 3]);
        unsigned Cw = pk2(p[i0 + 4], p[i0 + 5]);
        unsigned Dw = pk2(p[i0 + 6], p[i0 + 7]);
        unsigned xA = (unsigned)__shfl_xor((int)Aw, 32, 64);
        unsigned xB = (unsigned)__shfl_xor((int)Bw, 32, 64);
        unsigned xC = (unsigned)__shfl_xor((int)Cw, 32, 64);
        unsigned xD = (unsigned)__shfl_xor((int)Dw, 32, 64);
        union { unsigned u[4]; bf16x8 v; } pa;
        pa.u[0] = hi ? xC : Aw;
        pa.u[1] = hi ? xD : Bw;
        pa.u[2] = hi ? Cw : xA;
        pa.u[3] = hi ? Dw : xB;
        const int cw = (((ks * 2 + hi) ^ swz) * 8);
        bf16x8 va0 = *(const bf16x8*)&Vt[l31 * 128 + sub * 64 + cw];
        bf16x8 va1 = *(const bf16x8*)&Vt[(l31 + 32) * 128 + sub * 64 + cw];
        ot0 = mfma32(va0, pa.v, ot0);
        ot1 = mfma32(va1, pa.v, ot1);
      }
    }
  }

  const int b = bh >> 4, h = bh & 15;
  const float inv = 1.f / l;
  const size_t orow = ((size_t)(b * NT + qrow)) * ND + h * 64;
#pragma unroll
  for (int g = 0; g < 4; g++) {
    bf16x4 w0, w1;
#pragma unroll
    for (int c = 0; c < 4; c++) {
      w0[c] = (bf16)(ot0[g * 4 + c] * inv);
      w1[c] = (bf16)(ot1[g * 4 + c] * inv);
    }
    *(bf16x4*)(attn_out + orow + g * 8 + 4 * hi) = w0;
    *(bf16x4*)(attn_out + orow + 32 + g * 8 + 4 * hi) = w1;
  }
}

// ---------------- capacity scan (single wave, token order, batched loads) ----------------
__global__ void scan_k(const int* __restrict__ idx, int* __restrict__ slot,
                       int* __restrict__ kept) {
  const int lane = threadIdx.x;
  int base[8];
#pragma unroll
  for (int e = 0; e < 8; e++) base[e] = 0;
  const unsigned long long lm = (lane == 63) ? ~0ull : ((1ull << (lane + 1)) - 1);
  for (int cb = 0; cb < 64; cb += 8) {
    int2 ev[8];  // batch 8 chunks' (e0,e1) -- loads issue together, latency amortized
#pragma unroll
    for (int u = 0; u < 8; u++)
      ev[u] = ((const int2*)idx)[(cb + u) * 64 + lane];
#pragma unroll
    for (int u = 0; u < 8; u++) {
      const int n = (cb + u) * 64 + lane;
      const int e0 = ev[u].x, e1 = ev[u].y;
      int s0 = 0, s1 = 0;
#pragma unroll
      for (int e = 0; e < 8; e++) {
        unsigned long long m0 = __ballot(e0 == e);
        unsigned long long m1 = __ballot(e1 == e);
        unsigned long long m = m0 | m1;
        int pref = __popcll(m & lm);
        if (e0 == e) s0 = base[e] + pref - 1;
        if (e1 == e) s1 = base[e] + pref - 1;
        base[e] += __popcll(m);
      }
      slot[n * 2] = s0; slot[n * 2 + 1] = s1;
      kept[n * 2] = (s0 < NCAP) ? 1 : 0;
      kept[n * 2 + 1] = (s1 < NCAP) ? 1 : 0;
    }
  }
}

// ---------------- scatter tokens into expert buffers ----------------
__global__ __launch_bounds__(64) void scatter_k(const float* __restrict__ moe_in,
                                                const int* __restrict__ idx,
                                                const int* __restrict__ slot,
                                                const int* __restrict__ kept,
                                                bf16* __restrict__ buf) {
  const int a = blockIdx.x;
  if (!kept[a]) return;
  const int n = a >> 1;
  const int e = idx[a], s = slot[a];
  const float* src = moe_in + (size_t)n * ND;
  bf16* dst = buf + ((size_t)e * NCAP + s) * ND;
  for (int c = threadIdx.x * 4; c < 1024; c += 256) {
    f32x4 v = *(const f32x4*)(src + c);
    bf16x4 o;
    o[0] = (bf16)v[0]; o[1] = (bf16)v[1]; o[2] = (bf16)v[2]; o[3] = (bf16)v[3];
    *(bf16x4*)(dst + c) = o;
  }
}

// ---------------- gather expert outputs (2 K-partials + b2, gate) + residual ----------------
__global__ __launch_bounds__(256) void gather_k(const float* __restrict__ h,
                                                const bf16* __restrict__ eout,
                                                const int* __restrict__ idx,
                                                const int* __restrict__ slot,
                                                const int* __restrict__ kept,
                                                const float* __restrict__ gv,
                                                const float* __restrict__ b2,
                                                float* __restrict__ out) {
  const size_t PS = (size_t)NE * NCAP * ND;  // partial stride
  const int n = blockIdx.x;
  const int k0 = kept[n * 2], k1 = kept[n * 2 + 1];
  const int i0 = idx[n * 2], i1 = idx[n * 2 + 1];
  const float g0 = k0 ? gv[n * 2] : 0.f;
  const float g1 = k1 ? gv[n * 2 + 1] : 0.f;
  const size_t r0 = k0 ? ((size_t)i0 * NCAP + slot[n * 2]) * ND : 0;
  const size_t r1 = k1 ? ((size_t)i1 * NCAP + slot[n * 2 + 1]) * ND : 0;
  const int c = threadIdx.x * 4;
  f32x4 o = *(const f32x4*)(h + (size_t)n * ND + c);
  if (k0) {
    bf16x4 ea = *(const bf16x4*)(eout + r0 + c);
    bf16x4 eb = *(const bf16x4*)(eout + PS + r0 + c);
    f32x4 bb = *(const f32x4*)(b2 + i0 * ND + c);
#pragma unroll
    for (int cc = 0; cc < 4; cc++)
      o[cc] += g0 * ((float)ea[cc] + (float)eb[cc] + bb[cc]);
  }
  if (k1) {
    bf16x4 ea = *(const bf16x4*)(eout + r1 + c);
    bf16x4 eb = *(const bf16x4*)(eout + PS + r1 + c);
    f32x4 bb = *(const f32x4*)(b2 + i1 * ND + c);
#pragma unroll
    for (int cc = 0; cc < 4; cc++)
      o[cc] += g1 * ((float)ea[cc] + (float)eb[cc] + bb[cc]);
  }
  *(f32x4*)(out + (size_t)n * ND + c) = o;
}

// ---------------- launcher ----------------
extern "C" void kernel_launch(void* const* d_in, const int* in_sizes, int n_in,
                              void* d_out, int out_size, void* d_ws, size_t ws_size,
                              hipStream_t stream) {
  (void)in_sizes; (void)n_in; (void)out_size;
  const float* x      = (const float*)d_in[0];
  const float* ln1_g  = (const float*)d_in[1];
  const float* ln1_b  = (const float*)d_in[2];
  const float* w_qkv  = (const float*)d_in[3];
  const float* w_proj = (const float*)d_in[4];
  const float* ln2_g  = (const float*)d_in[5];
  const float* ln2_b  = (const float*)d_in[6];
  const float* w_gate = (const float*)d_in[7];
  const float* w1     = (const float*)d_in[8];
  const float* b1     = (const float*)d_in[9];
  const float* w2     = (const float*)d_in[10];
  const float* b2     = (const float*)d_in[11];
  float* out = (float*)d_out;

  char* ws = (char*)d_ws;
  size_t off = 0;
  auto alloc = [&](size_t bytes) -> char* {
    char* p = ws + off;
    off += (bytes + 255) & ~(size_t)255;
    return p;
  };
  bf16* w1t    = (bf16*)alloc((size_t)NE * NDFF * ND * 2);     // 67.1 MB
  bf16* w2t    = (bf16*)alloc((size_t)NE * ND * NDFF * 2);     // 67.1 MB
  bf16* wqkvb  = (bf16*)alloc((size_t)3 * ND * ND * 2);        // 6.29 MB
  bf16* wprojb = (bf16*)alloc((size_t)ND * ND * 2);            // 2.10 MB
  float* hbufr = (float*)alloc((size_t)NTOK * ND * 4);         // h, 16.78 MB
  float* moein = (float*)alloc((size_t)NTOK * ND * 4);         // 16.78 MB
  float* ropet = (float*)alloc((size_t)NT * 32 * 2 * 4);       // 0.52 MB
  int*   idx   = (int*)alloc((size_t)NTOK * 2 * 4);
  int*   slot  = (int*)alloc((size_t)NTOK * 2 * 4);
  int*   kept  = (int*)alloc((size_t)NTOK * 2 * 4);
  float* gv    = (float*)alloc((size_t)NTOK * 2 * 4);
  char*  S     = alloc((size_t)62914560);                      // 62.9 MB shared region
  if (off > ws_size) return;

  // phase A layout (attention)
  const size_t MB8 = (size_t)8388608;
  bf16* xn    = (bf16*)(S);
  bf16* qp    = (bf16*)(S + MB8);
  bf16* kp    = (bf16*)(S + 2 * MB8);
  bf16* vp    = (bf16*)(S + 3 * MB8);
  bf16* attnp = (bf16*)(S + 4 * MB8);
  bf16* vTp   = (bf16*)(S);                       // alias xn (dead after qkv gemm)
  // phase B layout (MoE): hbuf [0,41.9M), buf [41.9,52.4M),
  // eout (2 bf16 partials, 21 MB) [41.9,62.9M) -- aliases buf after gemm1.
  bf16* hbuf  = (bf16*)(S);
  bf16* buf   = (bf16*)(S + (size_t)41943040);
  bf16* eout  = (bf16*)(S + (size_t)41943040);

  dim3 tb(32, 8);
  cvt_k<<<2048, 256, 0, stream>>>(w_qkv, wqkvb, 3 * ND * ND / 4);
  cvt_k<<<1024, 256, 0, stream>>>(w_proj, wprojb, ND * ND / 4);
  transpose_k<<<dim3(NDFF / 64, ND / 64, NE), 256, 0, stream>>>(w1, w1t, ND, NDFF);
  transpose_k<<<dim3(ND / 64, NDFF / 64, NE), 256, 0, stream>>>(w2, w2t, NDFF, ND);
  rope_tab_k<<<NT, 32, 0, stream>>>(ropet);
  ln_k<<<NTOK, 256, 0, stream>>>(x, ln1_g, ln1_b, xn);
  // qkv: grid 768 (3 blocks/CU) -> gload 1-phase
  gemm_bt_k<EPI_SPLIT_QKV, 0, false, 1, false>
      <<<dim3(3 * ND / 128, NTOK / 128, 1), 256, 0, stream>>>(
      xn, wqkvb, NTOK, 3 * ND, ND, 0, 0, 0, 0, nullptr, nullptr, qp, kp, vp);
  transpose_v_k<<<dim3(NT / 32, HD_ / 32, NB * NH), tb, 0, stream>>>(vp, vTp);
  rope_k<<<dim3(NT / 4, NB * NH), 256, 0, stream>>>(qp, kp, ropet);
  attn_k<<<512, 256, 0, stream>>>(qp, kp, vTp, attnp);
  // proj: grid 256 (1 block/CU) -> reg-staged 2-deep pipelined, padded LDS
  gemm_bt_k<EPI_ADD_X, 1, true, 1, false>
      <<<dim3(ND / 128, NTOK / 128, 1), 256, 0, stream>>>(
      attnp, wprojb, NTOK, ND, ND, 0, 0, 0, 0, nullptr, x, hbufr, nullptr, nullptr);
  // fused ln2 + gating
  ln_gate_k<<<NTOK, 256, 0, stream>>>(hbufr, ln2_g, ln2_b, w_gate, moein, idx, gv);
  scan_k<<<1, 64, 0, stream>>>(idx, slot, kept);
  scatter_k<<<NTOK * 2, 64, 0, stream>>>(moein, idx, slot, kept, buf);
  // moe GEMM1: grid 1280 (5 blocks/CU) -> gload 1-phase, erff gelu, XCD swizzle
  gemm_bt_k<EPI_BIAS_GELU, 0, false, 1, true>
      <<<dim3(NDFF / 128, NCAP / 128, NE), 256, 0, stream>>>(
      buf, w1t, NCAP, NDFF, ND, (size_t)NCAP * ND, (size_t)NDFF * ND,
      (size_t)NCAP * NDFF, NDFF, b1, nullptr, hbuf, nullptr, nullptr);
  // moe GEMM2: split-K=2 (grid 640), reg-staged 2-deep, bf16 partials, XCD swizzle
  gemm_bt_k<EPI_STORE, 1, true, 2, true>
      <<<dim3(ND / 128, NCAP / 128, NE * 2), 256, 0, stream>>>(
      hbuf, w2t, NCAP, ND, NDFF, (size_t)NCAP * NDFF, (size_t)ND * NDFF,
      (size_t)NCAP * ND, 0, nullptr, nullptr, eout, nullptr, nullptr);
  gather_k<<<NTOK, 256, 0, stream>>>(hbufr, eout, idx, slot, kept, gv, b2, out);
}

// Round 20
// 419.035 us; speedup vs baseline: 1.0388x; 1.0035x over previous
//
#include <hip/hip_runtime.h>
#include <hip/hip_bf16.h>

typedef __bf16 bf16;
typedef __attribute__((ext_vector_type(8))) __bf16 bf16x8;
typedef __attribute__((ext_vector_type(4))) __bf16 bf16x4;
typedef __attribute__((ext_vector_type(4))) float f32x4;
typedef __attribute__((ext_vector_type(16))) float f32x16;

#define NB 2
#define NT 2048
#define ND 1024
#define NH 16
#define HD_ 64
#define NE 8
#define NCAP 640
#define NTOK 4096
#define NDFF 4096

static __device__ __forceinline__ f32x4 mfma16(bf16x8 a, bf16x8 b, f32x4 c) {
  return __builtin_amdgcn_mfma_f32_16x16x32_bf16(a, b, c, 0, 0, 0);
}
static __device__ __forceinline__ f32x16 mfma32(bf16x8 a, bf16x8 b, f32x16 c) {
  return __builtin_amdgcn_mfma_f32_32x32x16_bf16(a, b, c, 0, 0, 0);
}
static __device__ __forceinline__ unsigned pk2(float a, float b) {
  union { __bf16 h[2]; unsigned u; } z;
  z.h[0] = (__bf16)a; z.h[1] = (__bf16)b;
  return z.u;
}
static __device__ __forceinline__ void gload_lds16(const bf16* g, bf16* l) {
  __builtin_amdgcn_global_load_lds(
      (const __attribute__((address_space(1))) unsigned int*)g,
      (__attribute__((address_space(3))) unsigned int*)l, 16, 0, 0);
}

// ---------------- elementwise f32 -> bf16 convert ----------------
__global__ __launch_bounds__(256) void cvt_k(const float* __restrict__ in,
                                             bf16* __restrict__ out, int n4) {
  int i = blockIdx.x * 256 + threadIdx.x;
  int stride = gridDim.x * 256;
  for (; i < n4; i += stride) {
    f32x4 v = ((const f32x4*)in)[i];
    bf16x4 o;
    o[0] = (bf16)v[0]; o[1] = (bf16)v[1]; o[2] = (bf16)v[2]; o[3] = (bf16)v[3];
    ((bf16x4*)out)[i] = o;
  }
}

// ---------------- transpose f32 (R,C) -> bf16 (C,R), 64x64 tiles, batched z ----------------
__global__ __launch_bounds__(256) void transpose_k(const float* __restrict__ in,
                                                   bf16* __restrict__ out, int R, int C) {
  __shared__ float tile[64][65];
  const size_t zoff = (size_t)blockIdx.z * R * C;
  in += zoff; out += zoff;
  const int c0 = blockIdx.x * 64, r0 = blockIdx.y * 64;
  const int tx = threadIdx.x & 15, ty = threadIdx.x >> 4;  // 16 x 16
#pragma unroll
  for (int i = 0; i < 4; i++) {
    const int r = i * 16 + ty;
    f32x4 v = *(const f32x4*)(in + (size_t)(r0 + r) * C + c0 + tx * 4);
    *(f32x4*)&tile[r][tx * 4] = v;
  }
  __syncthreads();
#pragma unroll
  for (int i = 0; i < 4; i++) {
    const int rr = i * 16 + ty;  // output row within tile (= source col)
    bf16x4 o;
#pragma unroll
    for (int j = 0; j < 4; j++) o[j] = (bf16)tile[tx * 4 + j][rr];
    *(bf16x4*)(out + (size_t)(c0 + rr) * R + r0 + tx * 4) = o;
  }
}

// ---------------- transpose bf16 v (per bh: (T,HD) -> (HD,T)) ----------------
__global__ __launch_bounds__(256) void transpose_v_k(const bf16* __restrict__ v,
                                                     bf16* __restrict__ vT) {
  __shared__ bf16 tile[32][33];
  int bh = blockIdx.z;
  const bf16* in = v + (size_t)bh * NT * HD_;
  bf16* out = vT + (size_t)bh * HD_ * NT;
  int t0 = blockIdx.x * 32, d0 = blockIdx.y * 32;
  int tx = threadIdx.x, ty = threadIdx.y;
#pragma unroll
  for (int i = 0; i < 4; i++)
    tile[ty + i * 8][tx] = in[(size_t)(t0 + ty + i * 8) * HD_ + d0 + tx];
  __syncthreads();
#pragma unroll
  for (int i = 0; i < 4; i++)
    out[(size_t)(d0 + ty + i * 8) * NT + t0 + tx] = tile[tx][ty + i * 8];
}

// ---------------- rope sin/cos table ----------------
__global__ void rope_tab_k(float* __restrict__ tab) {
  int t = blockIdx.x, i = threadIdx.x;  // 32 threads
  float inv = powf(10000.f, -(float)(2 * i) * (1.f / 64.f));
  float ang = (float)t * inv;
  float s, c;
  sincosf(ang, &s, &c);
  tab[(t * 32 + i) * 2] = s;
  tab[(t * 32 + i) * 2 + 1] = c;
}

// ---------------- layernorm (row of 1024) -> bf16 ----------------
__global__ __launch_bounds__(256) void ln_k(const float* __restrict__ in,
                                            const float* __restrict__ g,
                                            const float* __restrict__ bb,
                                            bf16* __restrict__ outb) {
  const int row = blockIdx.x;
  const float* xr = in + (size_t)row * ND;
  const int tid = threadIdx.x, lane = tid & 63, wid = tid >> 6;
  f32x4 v = ((const f32x4*)xr)[tid];
  float s = v[0] + v[1] + v[2] + v[3];
  float sq = v[0] * v[0] + v[1] * v[1] + v[2] * v[2] + v[3] * v[3];
#pragma unroll
  for (int m = 1; m < 64; m <<= 1) {
    s += __shfl_xor(s, m, 64);
    sq += __shfl_xor(sq, m, 64);
  }
  __shared__ float red[8];
  if (lane == 0) { red[wid] = s; red[4 + wid] = sq; }
  __syncthreads();
  s = red[0] + red[1] + red[2] + red[3];
  sq = red[4] + red[5] + red[6] + red[7];
  float mean = s * (1.f / 1024.f);
  float var = sq * (1.f / 1024.f) - mean * mean;
  float rs = rsqrtf(var + 1e-5f);
#pragma unroll
  for (int c = 0; c < 4; c++) {
    int col = tid * 4 + c;
    float y = (v[c] - mean) * rs * g[col] + bb[col];
    outb[(size_t)row * ND + col] = (bf16)y;
  }
}

// ---------------- fused layernorm + gate (logits, softmax, top2) ----------------
__global__ __launch_bounds__(256) void ln_gate_k(const float* __restrict__ in,
                                                 const float* __restrict__ g,
                                                 const float* __restrict__ bb,
                                                 const float* __restrict__ w_gate,
                                                 float* __restrict__ moein,
                                                 int* __restrict__ idx,
                                                 float* __restrict__ gv) {
  const int row = blockIdx.x;
  const float* xr = in + (size_t)row * ND;
  const int tid = threadIdx.x, lane = tid & 63, wid = tid >> 6;
  f32x4 v = ((const f32x4*)xr)[tid];
  float s = v[0] + v[1] + v[2] + v[3];
  float sq = v[0] * v[0] + v[1] * v[1] + v[2] * v[2] + v[3] * v[3];
#pragma unroll
  for (int m = 1; m < 64; m <<= 1) {
    s += __shfl_xor(s, m, 64);
    sq += __shfl_xor(sq, m, 64);
  }
  __shared__ float red[8];
  if (lane == 0) { red[wid] = s; red[4 + wid] = sq; }
  __syncthreads();
  s = red[0] + red[1] + red[2] + red[3];
  sq = red[4] + red[5] + red[6] + red[7];
  float mean = s * (1.f / 1024.f);
  float var = sq * (1.f / 1024.f) - mean * mean;
  float rs = rsqrtf(var + 1e-5f);
  f32x4 y;
#pragma unroll
  for (int c = 0; c < 4; c++) {
    int col = tid * 4 + c;
    y[c] = (v[c] - mean) * rs * g[col] + bb[col];
  }
  *(f32x4*)(moein + (size_t)row * ND + tid * 4) = y;
  // gate logits: 8 dot products of the normalized row with w_gate rows
  float a[8];
#pragma unroll
  for (int e = 0; e < 8; e++) {
    f32x4 wv = *(const f32x4*)(w_gate + e * ND + tid * 4);
    a[e] = y[0] * wv[0] + y[1] * wv[1] + y[2] * wv[2] + y[3] * wv[3];
  }
#pragma unroll
  for (int e = 0; e < 8; e++)
#pragma unroll
    for (int m = 1; m < 64; m <<= 1) a[e] += __shfl_xor(a[e], m, 64);
  __shared__ float red2[4][8];
  if (lane < 8) red2[wid][lane] = a[lane];
  __syncthreads();
  if (tid == 0) {
    float t[8];
#pragma unroll
    for (int e = 0; e < 8; e++)
      t[e] = red2[0][e] + red2[1][e] + red2[2][e] + red2[3][e];
    float mx = t[0];
#pragma unroll
    for (int e = 1; e < 8; e++) mx = fmaxf(mx, t[e]);
    float p[8], se = 0.f;
#pragma unroll
    for (int e = 0; e < 8; e++) { p[e] = expf(t[e] - mx); se += p[e]; }
    float inv = 1.f / se;
#pragma unroll
    for (int e = 0; e < 8; e++) p[e] *= inv;
    int i1 = 0; float v1 = p[0];
#pragma unroll
    for (int e = 1; e < 8; e++) if (p[e] > v1) { v1 = p[e]; i1 = e; }
    int i2 = -1; float v2 = -1.f;
#pragma unroll
    for (int e = 0; e < 8; e++) if (e != i1 && p[e] > v2) { v2 = p[e]; i2 = e; }
    idx[row * 2] = i1; idx[row * 2 + 1] = i2;
    gv[row * 2] = v1; gv[row * 2 + 1] = v2;
  }
}

// ---------------- GEMM: C(M,N) = A(M,K) * B(N,K)^T, bf16 in, f32 accum ----------------
// STAGE=0: m97 gload_lds 1-phase (linear LDS), right at >=3 blocks/CU.
// STAGE=1: reg-staged 2-DEEP pipelined (named buffers, step-unrolled x2 --
//   rule #20), right at low blocks/CU. Requires nst even (proj 16, GEMM2 32).
// NSPLIT (compile-time): split-K; EPI_STORE writes per-chunk bf16 partials.
// MSWZ: XCD-locality swizzle -- m-tiles sharing one B-panel land on one XCD.
#define EPI_SPLIT_QKV 0
#define EPI_ADD_X 1
#define EPI_BIAS_GELU 2
#define EPI_STORE 3

template <int EPI, int STAGE, bool PAD, int NSPLIT, bool MSWZ>
__global__ __launch_bounds__(256) void gemm_bt_k(
    const bf16* __restrict__ A, const bf16* __restrict__ Bw,
    const int M, const int N, const int K,
    const size_t zA, const size_t zB, const size_t zOut, const size_t zBias,
    const float* __restrict__ bias, const float* __restrict__ Xadd,
    void* __restrict__ Out, bf16* __restrict__ k_out, bf16* __restrict__ v_out) {
  int bx = blockIdx.x, by = blockIdx.y, bz = blockIdx.z;
  if constexpr (MSWZ) {
    const int gx = gridDim.x, gy = gridDim.y;
    int lin = bx + gx * (by + gy * bz);
    int xcd = lin & 7;
    int t = lin >> 3;
    by = t % gy;              // m-tile
    int gq = t / gy;
    int gg = gq * 8 + xcd;    // (n, z) panel id
    bx = gg % gx;
    bz = gg / gx;
  }
  const int z = bz;
  const int ze = z / NSPLIT;
  const int kc = z % NSPLIT;
  const int klen = K / NSPLIT;
  const int kb = kc * klen;
  const int nst = klen / 64;
  const int m0 = by * 128, n0 = bx * 128;
  const int tid = threadIdx.x, lane = tid & 63, wid = tid >> 6;
  const int wm = (wid >> 1) * 64, wn = (wid & 1) * 64;
  const int l15 = lane & 15, ksl = lane >> 4;
  constexpr int LDB = (STAGE == 1 && PAD) ? 72 : 64;
  __shared__ __align__(16) bf16 As[128 * LDB];
  __shared__ __align__(16) bf16 Bs[128 * LDB];
  f32x4 acc[4][4];
#pragma unroll
  for (int i = 0; i < 4; i++)
#pragma unroll
    for (int j = 0; j < 4; j++) acc[i][j] = (f32x4){0.f, 0.f, 0.f, 0.f};

  if constexpr (STAGE == 0) {
    const int lr = lane >> 3, lc = (lane & 7) * 8;
    const bf16* Ag = A + zA * ze + (size_t)(m0 + wid * 32 + lr) * K + kb + lc;
    const bf16* Bg = Bw + zB * ze + (size_t)(n0 + wid * 32 + lr) * K + kb + lc;
    for (int s = 0; s < nst; ++s) {
      __syncthreads();
#pragma unroll
      for (int it = 0; it < 4; it++) {
        gload_lds16(Ag + (size_t)(it * 8) * K + s * 64, &As[(wid * 32 + it * 8) * 64]);
        gload_lds16(Bg + (size_t)(it * 8) * K + s * 64, &Bs[(wid * 32 + it * 8) * 64]);
      }
      __syncthreads();
#pragma unroll
      for (int kk = 0; kk < 2; kk++) {
        bf16x8 af[4], bfr[4];
        const int ko = kk * 32 + ksl * 8;
#pragma unroll
        for (int i = 0; i < 4; i++)
          af[i] = *(const bf16x8*)&As[(wm + i * 16 + l15) * 64 + ko];
#pragma unroll
        for (int j = 0; j < 4; j++)
          bfr[j] = *(const bf16x8*)&Bs[(wn + j * 16 + l15) * 64 + ko];
#pragma unroll
        for (int i = 0; i < 4; i++)
#pragma unroll
          for (int j = 0; j < 4; j++)
            acc[i][j] = mfma16(af[i], bfr[j], acc[i][j]);
      }
    }
  } else {
    // reg-staged 2-deep pipelined: thread covers (row = flat>>3, col = (flat&7)*8)
    const int sr = tid >> 3, sc = (tid & 7) * 8;
    const bf16* Ag = A + zA * ze + (size_t)(m0 + sr) * K + kb + sc;
    const bf16* Bg = Bw + zB * ze + (size_t)(n0 + sr) * K + kb + sc;
    bf16x8 avA[4], bvA[4], avB[4], bvB[4];
#pragma unroll
    for (int it = 0; it < 4; it++) {
      avA[it] = *(const bf16x8*)(Ag + (size_t)(it * 32) * K);
      bvA[it] = *(const bf16x8*)(Bg + (size_t)(it * 32) * K);
    }
#pragma unroll
    for (int it = 0; it < 4; it++) {
      avB[it] = *(const bf16x8*)(Ag + (size_t)(it * 32) * K + 64);
      bvB[it] = *(const bf16x8*)(Bg + (size_t)(it * 32) * K + 64);
    }
    auto compute = [&]() {
#pragma unroll
      for (int kk = 0; kk < 2; kk++) {
        bf16x8 af[4], bfr[4];
        const int ko = kk * 32 + ksl * 8;
#pragma unroll
        for (int i = 0; i < 4; i++)
          af[i] = *(const bf16x8*)&As[(wm + i * 16 + l15) * LDB + ko];
#pragma unroll
        for (int j = 0; j < 4; j++)
          bfr[j] = *(const bf16x8*)&Bs[(wn + j * 16 + l15) * LDB + ko];
#pragma unroll
        for (int i = 0; i < 4; i++)
#pragma unroll
          for (int j = 0; j < 4; j++)
            acc[i][j] = mfma16(af[i], bfr[j], acc[i][j]);
      }
    };
    for (int s = 0; s < nst; s += 2) {
      // even step: buffer A holds tile s
      __syncthreads();  // previous step's LDS reads done
#pragma unroll
      for (int it = 0; it < 4; it++) {
        *(bf16x8*)&As[(sr + it * 32) * LDB + sc] = avA[it];
        *(bf16x8*)&Bs[(sr + it * 32) * LDB + sc] = bvA[it];
      }
      __syncthreads();  // tile s visible
      if (s + 2 < nst) {  // issue loads for tile s+2; ~2 steps to land
#pragma unroll
        for (int it = 0; it < 4; it++) {
          avA[it] = *(const bf16x8*)(Ag + (size_t)(it * 32) * K + (s + 2) * 64);
          bvA[it] = *(const bf16x8*)(Bg + (size_t)(it * 32) * K + (s + 2) * 64);
        }
      }
      compute();
      // odd step: buffer B holds tile s+1
      __syncthreads();
#pragma unroll
      for (int it = 0; it < 4; it++) {
        *(bf16x8*)&As[(sr + it * 32) * LDB + sc] = avB[it];
        *(bf16x8*)&Bs[(sr + it * 32) * LDB + sc] = bvB[it];
      }
      __syncthreads();
      if (s + 3 < nst) {
#pragma unroll
        for (int it = 0; it < 4; it++) {
          avB[it] = *(const bf16x8*)(Ag + (size_t)(it * 32) * K + (s + 3) * 64);
          bvB[it] = *(const bf16x8*)(Bg + (size_t)(it * 32) * K + (s + 3) * 64);
        }
      }
      compute();
    }
  }

#pragma unroll
  for (int i = 0; i < 4; i++) {
#pragma unroll
    for (int j = 0; j < 4; j++) {
      const int mb = m0 + wm + i * 16 + ksl * 4;
      const int nc = n0 + wn + j * 16 + l15;
#pragma unroll
      for (int r = 0; r < 4; r++) {
        const int mr = mb + r;
        float vacc = acc[i][j][r];
        if constexpr (EPI == EPI_SPLIT_QKV) {
          const int h = nc / 192;
          const int rr = nc - h * 192;
          const int which = rr >> 6;
          const int d = rr & 63;
          const int b = mr >> 11, t = mr & 2047;
          bf16* dst = (which == 0) ? (bf16*)Out : (which == 1 ? k_out : v_out);
          dst[(((size_t)(b * NH + h)) * NT + t) * HD_ + d] = (bf16)vacc;
        } else if constexpr (EPI == EPI_ADD_X) {
          ((float*)Out)[(size_t)mr * N + nc] = vacc + Xadd[(size_t)mr * N + nc];
        } else if constexpr (EPI == EPI_BIAS_GELU) {
          // exact erf gelu -- PINNED. Measured optimum (VGPR 80, Occ 26%).
          // All cheap-gelu forms (div/rcp/raw-exp2) push VGPR to 92 and
          // cost an occupancy wave: r11/r13/r16 all regressed ~10 us.
          float x = vacc + bias[zBias * ze + nc];
          float gl = 0.5f * x * (1.f + erff(x * 0.70710678118654752f));
          ((bf16*)Out)[zOut * ze + (size_t)mr * N + nc] = (bf16)gl;
        } else {  // EPI_STORE: per-K-chunk bf16 partial (chunk stride = zOut*NE)
          ((bf16*)Out)[((size_t)kc * NE + ze) * zOut + (size_t)mr * N + nc] = (bf16)vacc;
        }
      }
    }
  }
}

// ---------------- rope apply (in-place on q,k); q also scaled by 0.125*log2(e) ----------------
__global__ __launch_bounds__(256) void rope_k(bf16* __restrict__ q, bf16* __restrict__ k,
                                              const float* __restrict__ tab) {
  const int bh = blockIdx.y;
  const int t = blockIdx.x * 4 + (threadIdx.x >> 6);
  const int d = threadIdx.x & 63;
  const size_t row = ((size_t)bh * NT + t) * HD_;
  const int i = d & 31;
  const float sn = tab[(t * 32 + i) * 2], cs = tab[(t * 32 + i) * 2 + 1];
  {
    float a = (float)q[row + d];
    float b2 = (float)q[row + (d ^ 32)];
    float o = (d < 32) ? (a * cs - b2 * sn) : (b2 * sn + a * cs);
    q[row + d] = (bf16)(o * 0.18033688011112042f);  // 0.125 * log2(e)
  }
  {
    float a = (float)k[row + d];
    float b2 = (float)k[row + (d ^ 32)];
    float o = (d < 32) ? (a * cs - b2 * sn) : (b2 * sn + a * cs);
    k[row + d] = (bf16)o;
  }
}

// ---------------- flash attention: swapped 32x32 MFMA, in-register softmax ----------------
// KVBLK=128: stage 128 KV rows per barrier pair (Kt[128][64], Vt[64][128],
// 32 KB LDS), compute the two 64-row subtiles sequentially -- halves barrier
// rounds (qt+1 vs 2qt+2). exp2 via raw v_exp_f32 builtin (r16: ~7 us win).
__global__ __launch_bounds__(256) void attn_k(const bf16* __restrict__ q,
                                              const bf16* __restrict__ k,
                                              const bf16* __restrict__ vT,
                                              bf16* __restrict__ attn_out) {
  __shared__ __align__(16) bf16 Kt[128 * 64];
  __shared__ __align__(16) bf16 Vt[64 * 128];
  const int bid = blockIdx.x;
  const int bh = bid & 31;
  const int ti = (bid >> 5) & 7;
  const int qt = (bid >> 8) ? (15 - ti) : ti;  // causal balance: CU pairs (t,15-t)
  const int q0 = qt * 128;
  const int tid = threadIdx.x, lane = tid & 63, wid = tid >> 6;
  const int l31 = lane & 31, hi = lane >> 5;
  const int q0w = q0 + wid * 32;
  const int qrow = q0w + l31;
  const size_t base = (size_t)bh * (NT * HD_);
  const size_t baseT = (size_t)bh * (HD_ * NT);

  bf16x8 qf[4];
#pragma unroll
  for (int ks = 0; ks < 4; ks++)
    qf[ks] = *(const bf16x8*)(q + base + (size_t)qrow * HD_ + ks * 16 + hi * 8);

  f32x16 ot0, ot1;
#pragma unroll
  for (int r = 0; r < 16; r++) { ot0[r] = 0.f; ot1[r] = 0.f; }
  float m2 = -1e30f, l = 0.f;

  const int nrounds = qt + 1;  // 128 KV rows per round
  const int swz = (l31 & 7);
  const int strow = tid >> 3, stc = tid & 7;
  const int cw0 = ((stc ^ (strow & 7)) * 8);  // swizzle const across +32/+64 rows
  bf16x8 kr[4], vr[4];
#pragma unroll
  for (int rr = 0; rr < 4; rr++)  // preload round 0: K rows 0..127
    kr[rr] = *(const bf16x8*)(k + base + (size_t)(strow + rr * 32) * HD_ + stc * 8);
#pragma unroll
  for (int rr = 0; rr < 2; rr++)
#pragma unroll
    for (int h2 = 0; h2 < 2; h2++)  // V: d rows 0..63, kv cols 0..127
      vr[rr * 2 + h2] = *(const bf16x8*)(vT + baseT + (size_t)(strow + rr * 32) * NT +
                                         h2 * 64 + stc * 8);

  for (int ro = 0; ro < nrounds; ro++) {
    const int kv0r = ro * 128;
    __syncthreads();  // previous round's LDS reads done
#pragma unroll
    for (int rr = 0; rr < 4; rr++)
      *(bf16x8*)&Kt[(strow + rr * 32) * 64 + cw0] = kr[rr];
#pragma unroll
    for (int rr = 0; rr < 2; rr++)
#pragma unroll
      for (int h2 = 0; h2 < 2; h2++)
        *(bf16x8*)&Vt[(strow + rr * 32) * 128 + h2 * 64 + cw0] = vr[rr * 2 + h2];
    __syncthreads();  // round visible
    if (ro + 1 < nrounds) {  // issue next-round loads; hide under compute
      const int kn = kv0r + 128;
#pragma unroll
      for (int rr = 0; rr < 4; rr++)
        kr[rr] = *(const bf16x8*)(k + base + (size_t)(kn + strow + rr * 32) * HD_ + stc * 8);
#pragma unroll
      for (int rr = 0; rr < 2; rr++)
#pragma unroll
        for (int h2 = 0; h2 < 2; h2++)
          vr[rr * 2 + h2] = *(const bf16x8*)(vT + baseT + (size_t)(strow + rr * 32) * NT +
                                             kn + h2 * 64 + stc * 8);
    }

#pragma unroll
    for (int sub = 0; sub < 2; sub++) {
      const int kv0 = kv0r + sub * 64;
      if (kv0 > q0w + 31) break;  // later subs only larger -- done this round

      f32x16 s0, s1;
#pragma unroll
      for (int r = 0; r < 16; r++) { s0[r] = 0.f; s1[r] = 0.f; }
#pragma unroll
      for (int ks = 0; ks < 4; ks++) {
        const int cw = (((ks * 2 + hi) ^ swz) * 8);
        bf16x8 ka0 = *(const bf16x8*)&Kt[(sub * 64 + l31) * 64 + cw];
        bf16x8 ka1 = *(const bf16x8*)&Kt[(sub * 64 + l31 + 32) * 64 + cw];
        s0 = mfma32(ka0, qf[ks], s0);
        s1 = mfma32(ka1, qf[ks], s1);
      }

      float p[32];
#pragma unroll
      for (int r = 0; r < 16; r++) { p[r] = s0[r]; p[16 + r] = s1[r]; }
      if (kv0 + 63 > q0w) {  // diagonal tile: causal mask
#pragma unroll
        for (int s2 = 0; s2 < 2; s2++)
#pragma unroll
          for (int r = 0; r < 16; r++) {
            int kvg = kv0 + s2 * 32 + (r & 3) + 8 * (r >> 2) + 4 * hi;
            if (kvg > qrow) p[s2 * 16 + r] = -1e30f;
          }
      }
      float tm = p[0];
#pragma unroll
      for (int r = 1; r < 32; r++) tm = fmaxf(tm, p[r]);
      tm = fmaxf(tm, __shfl_xor(tm, 32, 64));
      if (!__all(tm <= m2 + 8.f)) {  // defer-max
        float mn = fmaxf(m2, tm);
        float sf = __builtin_amdgcn_exp2f(m2 - mn);
        m2 = mn;
        l *= sf;
#pragma unroll
        for (int r = 0; r < 16; r++) { ot0[r] *= sf; ot1[r] *= sf; }
      }
      float ts = 0.f;
#pragma unroll
      for (int r = 0; r < 32; r++) { p[r] = __builtin_amdgcn_exp2f(p[r] - m2); ts += p[r]; }
      ts += __shfl_xor(ts, 32, 64);
      l += ts;

#pragma unroll
      for (int ks = 0; ks < 4; ks++) {
        const int i0 = (ks >> 1) * 16 + (ks & 1) * 8;
        unsigned Aw = pk2(p[i0 + 0], p[i0 + 1]);
        unsigned Bw = pk2(p[i0 + 2], p[i0 + 3]);
        unsigned Cw = pk2(p[i0 + 4], p[i0 + 5]);
        unsigned Dw = pk2(p[i0 + 6], p[i0 + 7]);
        unsigned xA = (unsigned)__shfl_xor((int)Aw, 32, 64);
        unsigned xB = (unsigned)__shfl_xor((int)Bw, 32, 64);
        unsigned xC = (unsigned)__shfl_xor((int)Cw, 32, 64);
        unsigned xD = (unsigned)__shfl_xor((int)Dw, 32, 64);
        union { unsigned u[4]; bf16x8 v; } pa;
        pa.u[0] = hi ? xC : Aw;
        pa.u[1] = hi ? xD : Bw;
        pa.u[2] = hi ? Cw : xA;
        pa.u[3] = hi ? Dw : xB;
        const int cw = (((ks * 2 + hi) ^ swz) * 8);
        bf16x8 va0 = *(const bf16x8*)&Vt[l31 * 128 + sub * 64 + cw];
        bf16x8 va1 = *(const bf16x8*)&Vt[(l31 + 32) * 128 + sub * 64 + cw];
        ot0 = mfma32(va0, pa.v, ot0);
        ot1 = mfma32(va1, pa.v, ot1);
      }
    }
  }

  const int b = bh >> 4, h = bh & 15;
  const float inv = 1.f / l;
  const size_t orow = ((size_t)(b * NT + qrow)) * ND + h * 64;
#pragma unroll
  for (int g = 0; g < 4; g++) {
    bf16x4 w0, w1;
#pragma unroll
    for (int c = 0; c < 4; c++) {
      w0[c] = (bf16)(ot0[g * 4 + c] * inv);
      w1[c] = (bf16)(ot1[g * 4 + c] * inv);
    }
    *(bf16x4*)(attn_out + orow + g * 8 + 4 * hi) = w0;
    *(bf16x4*)(attn_out + orow + 32 + g * 8 + 4 * hi) = w1;
  }
}

// ---------------- capacity scan (single wave, token order, batched loads) ----------------
__global__ void scan_k(const int* __restrict__ idx, int* __restrict__ slot,
                       int* __restrict__ kept) {
  const int lane = threadIdx.x;
  int base[8];
#pragma unroll
  for (int e = 0; e < 8; e++) base[e] = 0;
  const unsigned long long lm = (lane == 63) ? ~0ull : ((1ull << (lane + 1)) - 1);
  for (int cb = 0; cb < 64; cb += 8) {
    int2 ev[8];  // batch 8 chunks' (e0,e1) -- loads issue together, latency amortized
#pragma unroll
    for (int u = 0; u < 8; u++)
      ev[u] = ((const int2*)idx)[(cb + u) * 64 + lane];
#pragma unroll
    for (int u = 0; u < 8; u++) {
      const int n = (cb + u) * 64 + lane;
      const int e0 = ev[u].x, e1 = ev[u].y;
      int s0 = 0, s1 = 0;
#pragma unroll
      for (int e = 0; e < 8; e++) {
        unsigned long long m0 = __ballot(e0 == e);
        unsigned long long m1 = __ballot(e1 == e);
        unsigned long long m = m0 | m1;
        int pref = __popcll(m & lm);
        if (e0 == e) s0 = base[e] + pref - 1;
        if (e1 == e) s1 = base[e] + pref - 1;
        base[e] += __popcll(m);
      }
      slot[n * 2] = s0; slot[n * 2 + 1] = s1;
      kept[n * 2] = (s0 < NCAP) ? 1 : 0;
      kept[n * 2 + 1] = (s1 < NCAP) ? 1 : 0;
    }
  }
}

// ---------------- scatter tokens into expert buffers ----------------
__global__ __launch_bounds__(64) void scatter_k(const float* __restrict__ moe_in,
                                                const int* __restrict__ idx,
                                                const int* __restrict__ slot,
                                                const int* __restrict__ kept,
                                                bf16* __restrict__ buf) {
  const int a = blockIdx.x;
  if (!kept[a]) return;
  const int n = a >> 1;
  const int e = idx[a], s = slot[a];
  const float* src = moe_in + (size_t)n * ND;
  bf16* dst = buf + ((size_t)e * NCAP + s) * ND;
  for (int c = threadIdx.x * 4; c < 1024; c += 256) {
    f32x4 v = *(const f32x4*)(src + c);
    bf16x4 o;
    o[0] = (bf16)v[0]; o[1] = (bf16)v[1]; o[2] = (bf16)v[2]; o[3] = (bf16)v[3];
    *(bf16x4*)(dst + c) = o;
  }
}

// ---------------- gather expert outputs (2 K-partials + b2, gate) + residual ----------------
__global__ __launch_bounds__(256) void gather_k(const float* __restrict__ h,
                                                const bf16* __restrict__ eout,
                                                const int* __restrict__ idx,
                                                const int* __restrict__ slot,
                                                const int* __restrict__ kept,
                                                const float* __restrict__ gv,
                                                const float* __restrict__ b2,
                                                float* __restrict__ out) {
  const size_t PS = (size_t)NE * NCAP * ND;  // partial stride
  const int n = blockIdx.x;
  const int k0 = kept[n * 2], k1 = kept[n * 2 + 1];
  const int i0 = idx[n * 2], i1 = idx[n * 2 + 1];
  const float g0 = k0 ? gv[n * 2] : 0.f;
  const float g1 = k1 ? gv[n * 2 + 1] : 0.f;
  const size_t r0 = k0 ? ((size_t)i0 * NCAP + slot[n * 2]) * ND : 0;
  const size_t r1 = k1 ? ((size_t)i1 * NCAP + slot[n * 2 + 1]) * ND : 0;
  const int c = threadIdx.x * 4;
  f32x4 o = *(const f32x4*)(h + (size_t)n * ND + c);
  if (k0) {
    bf16x4 ea = *(const bf16x4*)(eout + r0 + c);
    bf16x4 eb = *(const bf16x4*)(eout + PS + r0 + c);
    f32x4 bb = *(const f32x4*)(b2 + i0 * ND + c);
#pragma unroll
    for (int cc = 0; cc < 4; cc++)
      o[cc] += g0 * ((float)ea[cc] + (float)eb[cc] + bb[cc]);
  }
  if (k1) {
    bf16x4 ea = *(const bf16x4*)(eout + r1 + c);
    bf16x4 eb = *(const bf16x4*)(eout + PS + r1 + c);
    f32x4 bb = *(const f32x4*)(b2 + i1 * ND + c);
#pragma unroll
    for (int cc = 0; cc < 4; cc++)
      o[cc] += g1 * ((float)ea[cc] + (float)eb[cc] + bb[cc]);
  }
  *(f32x4*)(out + (size_t)n * ND + c) = o;
}

// ---------------- launcher ----------------
extern "C" void kernel_launch(void* const* d_in, const int* in_sizes, int n_in,
                              void* d_out, int out_size, void* d_ws, size_t ws_size,
                              hipStream_t stream) {
  (void)in_sizes; (void)n_in; (void)out_size;
  const float* x      = (const float*)d_in[0];
  const float* ln1_g  = (const float*)d_in[1];
  const float* ln1_b  = (const float*)d_in[2];
  const float* w_qkv  = (const float*)d_in[3];
  const float* w_proj = (const float*)d_in[4];
  const float* ln2_g  = (const float*)d_in[5];
  const float* ln2_b  = (const float*)d_in[6];
  const float* w_gate = (const float*)d_in[7];
  const float* w1     = (const float*)d_in[8];
  const float* b1     = (const float*)d_in[9];
  const float* w2     = (const float*)d_in[10];
  const float* b2     = (const float*)d_in[11];
  float* out = (float*)d_out;

  char* ws = (char*)d_ws;
  size_t off = 0;
  auto alloc = [&](size_t bytes) -> char* {
    char* p = ws + off;
    off += (bytes + 255) & ~(size_t)255;
    return p;
  };
  bf16* w1t    = (bf16*)alloc((size_t)NE * NDFF * ND * 2);     // 67.1 MB
  bf16* w2t    = (bf16*)alloc((size_t)NE * ND * NDFF * 2);     // 67.1 MB
  bf16* wqkvb  = (bf16*)alloc((size_t)3 * ND * ND * 2);        // 6.29 MB
  bf16* wprojb = (bf16*)alloc((size_t)ND * ND * 2);            // 2.10 MB
  float* hbufr = (float*)alloc((size_t)NTOK * ND * 4);         // h, 16.78 MB
  float* moein = (float*)alloc((size_t)NTOK * ND * 4);         // 16.78 MB
  float* ropet = (float*)alloc((size_t)NT * 32 * 2 * 4);       // 0.52 MB
  int*   idx   = (int*)alloc((size_t)NTOK * 2 * 4);
  int*   slot  = (int*)alloc((size_t)NTOK * 2 * 4);
  int*   kept  = (int*)alloc((size_t)NTOK * 2 * 4);
  float* gv    = (float*)alloc((size_t)NTOK * 2 * 4);
  char*  S     = alloc((size_t)62914560);                      // 62.9 MB shared region
  if (off > ws_size) return;

  // phase A layout (attention)
  const size_t MB8 = (size_t)8388608;
  bf16* xn    = (bf16*)(S);
  bf16* qp    = (bf16*)(S + MB8);
  bf16* kp    = (bf16*)(S + 2 * MB8);
  bf16* vp    = (bf16*)(S + 3 * MB8);
  bf16* attnp = (bf16*)(S + 4 * MB8);
  bf16* vTp   = (bf16*)(S);                       // alias xn (dead after qkv gemm)
  // phase B layout (MoE): hbuf [0,41.9M), buf [41.9,52.4M),
  // eout (2 bf16 partials, 21 MB) [41.9,62.9M) -- aliases buf after gemm1.
  bf16* hbuf  = (bf16*)(S);
  bf16* buf   = (bf16*)(S + (size_t)41943040);
  bf16* eout  = (bf16*)(S + (size_t)41943040);

  dim3 tb(32, 8);
  cvt_k<<<2048, 256, 0, stream>>>(w_qkv, wqkvb, 3 * ND * ND / 4);
  cvt_k<<<1024, 256, 0, stream>>>(w_proj, wprojb, ND * ND / 4);
  transpose_k<<<dim3(NDFF / 64, ND / 64, NE), 256, 0, stream>>>(w1, w1t, ND, NDFF);
  transpose_k<<<dim3(ND / 64, NDFF / 64, NE), 256, 0, stream>>>(w2, w2t, NDFF, ND);
  rope_tab_k<<<NT, 32, 0, stream>>>(ropet);
  ln_k<<<NTOK, 256, 0, stream>>>(x, ln1_g, ln1_b, xn);
  // qkv: grid 768 (3 blocks/CU) -> gload 1-phase
  gemm_bt_k<EPI_SPLIT_QKV, 0, false, 1, false>
      <<<dim3(3 * ND / 128, NTOK / 128, 1), 256, 0, stream>>>(
      xn, wqkvb, NTOK, 3 * ND, ND, 0, 0, 0, 0, nullptr, nullptr, qp, kp, vp);
  transpose_v_k<<<dim3(NT / 32, HD_ / 32, NB * NH), tb, 0, stream>>>(vp, vTp);
  rope_k<<<dim3(NT / 4, NB * NH), 256, 0, stream>>>(qp, kp, ropet);
  attn_k<<<512, 256, 0, stream>>>(qp, kp, vTp, attnp);
  // proj: grid 256 (1 block/CU) -> reg-staged 2-deep pipelined, padded LDS
  gemm_bt_k<EPI_ADD_X, 1, true, 1, false>
      <<<dim3(ND / 128, NTOK / 128, 1), 256, 0, stream>>>(
      attnp, wprojb, NTOK, ND, ND, 0, 0, 0, 0, nullptr, x, hbufr, nullptr, nullptr);
  // fused ln2 + gating
  ln_gate_k<<<NTOK, 256, 0, stream>>>(hbufr, ln2_g, ln2_b, w_gate, moein, idx, gv);
  scan_k<<<1, 64, 0, stream>>>(idx, slot, kept);
  scatter_k<<<NTOK * 2, 64, 0, stream>>>(moein, idx, slot, kept, buf);
  // moe GEMM1: grid 1280 (5 blocks/CU) -> gload 1-phase, erff gelu, XCD swizzle
  gemm_bt_k<EPI_BIAS_GELU, 0, false, 1, true>
      <<<dim3(NDFF / 128, NCAP / 128, NE), 256, 0, stream>>>(
      buf, w1t, NCAP, NDFF, ND, (size_t)NCAP * ND, (size_t)NDFF * ND,
      (size_t)NCAP * NDFF, NDFF, b1, nullptr, hbuf, nullptr, nullptr);
  // moe GEMM2: split-K=2 (grid 640), reg-staged 2-deep, bf16 partials, XCD swizzle
  gemm_bt_k<EPI_STORE, 1, true, 2, true>
      <<<dim3(ND / 128, NCAP / 128, NE * 2), 256, 0, stream>>>(
      hbuf, w2t, NCAP, ND, NDFF, (size_t)NCAP * NDFF, (size_t)ND * NDFF,
      (size_t)NCAP * ND, 0, nullptr, nullptr, eout, nullptr, nullptr);
  gather_k<<<NTOK, 256, 0, stream>>>(hbufr, eout, idx, slot, kept, gv, b2, out);
}